// Round 2
// baseline (2074.761 us; speedup 1.0000x reference)
//
#include <hip/hip_runtime.h>
#include <float.h>
#include <math.h>

// Problem constants (from reference setup_inputs)
#define LQ   512
#define LL   4096      // key length
#define DD   64        // d_qk == d_v
#define KEEP 32        // MAX_SET_SIZE
#define QT   2         // query rows per block
#define NT   256       // threads per block
#define NTILES (LL / NT)   // 16
#define NB   8             // batches == XCD count

__device__ __forceinline__ float dot4(float4 a, float4 b) {
    return a.x * b.x + a.y * b.y + a.z * b.z + a.w * b.w;
}

__global__ __launch_bounds__(NT, 4) void ga_fused(
    const float* __restrict__ q,
    const float* __restrict__ kmat,
    const float* __restrict__ vmat,
    const int*   __restrict__ mask,
    float*       __restrict__ out)
{
    __shared__ float sc[QT][LL];                       // masked scores, 32 KB
    __shared__ float q_s[QT][DD];
    __shared__ unsigned long long mbits[QT][LL / 64];  // mask bitmap, 1 KB
    __shared__ float4 redv4[8][QT][16];                // mean-pool partials, 4 KB
    __shared__ float mean_s[QT][DD];
    __shared__ int   count_s[QT];

    const int t    = threadIdx.x;
    const int wave = t >> 6;
    const int lane = t & 63;
    // XCD swizzle: blockIdx % 8 is the XCD on MI355X's round-robin dispatch.
    // Pin batch == (blockIdx & 7) so each XCD's 4 MiB L2 holds exactly one
    // batch's k+v (2 MB) across all 256 of that batch's blocks.
    const int b      = blockIdx.x & (NB - 1);
    const int within = blockIdx.x >> 3;          // 0..255
    const int n0     = b * LQ + within * QT;     // first flat query row

    if (t < QT * DD) q_s[t >> 6][t & 63] = q[(size_t)(n0 + (t >> 6)) * DD + (t & 63)];
    __syncthreads();

    // ---- Phase A: scores (thread t owns key rows l == t mod 256) -----------
    float acc0[NTILES], acc1[NTILES];
    #pragma unroll
    for (int i = 0; i < NTILES; ++i) { acc0[i] = 0.f; acc1[i] = 0.f; }
    {
        const float4* k4  = reinterpret_cast<const float4*>(kmat + (size_t)b * LL * DD);
        const float4* q40 = reinterpret_cast<const float4*>(&q_s[0][0]);
        const float4* q41 = reinterpret_cast<const float4*>(&q_s[1][0]);
        #pragma unroll
        for (int c = 0; c < 4; ++c) {              // d-chunk: dims [c*16, c*16+16)
            float4 qa[4], qb[4];
            #pragma unroll
            for (int i = 0; i < 4; ++i) { qa[i] = q40[c * 4 + i]; qb[i] = q41[c * 4 + i]; }
            #pragma unroll
            for (int tile = 0; tile < NTILES; ++tile) {
                const float4* kr = k4 + (size_t)(tile * NT + t) * (DD / 4) + c * 4;
                #pragma unroll
                for (int i = 0; i < 4; ++i) {
                    float4 kk = kr[i];
                    acc0[tile] += dot4(kk, qa[i]);
                    acc1[tile] += dot4(kk, qb[i]);
                }
            }
        }
    }
    #pragma unroll
    for (int tile = 0; tile < NTILES; ++tile) {
        int l = tile * NT + t;
        int mv0 = mask[(size_t)n0 * LL + l];
        int mv1 = mask[(size_t)(n0 + 1) * LL + l];
        unsigned long long b0 = __ballot(mv0 != 0);
        unsigned long long b1 = __ballot(mv1 != 0);
        if (lane == 0) { mbits[0][tile * 4 + wave] = b0; mbits[1][tile * 4 + wave] = b1; }
        sc[0][l] = mv0 ? acc0[tile] * 0.125f : -FLT_MAX;
        sc[1][l] = mv1 ? acc1[tile] * 0.125f : -FLT_MAX;
    }
    __syncthreads();

    // ---- mask popcounts (wave w handles row w) ------------------------------
    if (wave < QT) {
        int c = (int)__popcll(mbits[wave][lane]);
        for (int off = 32; off >= 1; off >>= 1) c += __shfl_down(c, off);
        if (lane == 0) count_s[wave] = c;
    }

    // ---- Phase B: masked mean of v, float4-vectorized -----------------------
    {
        const int sub = t & 15;                    // d-range sub*4 .. sub*4+3
        const int grp = t >> 4;                    // 16 row groups
        const float4* v4 = reinterpret_cast<const float4*>(vmat + (size_t)b * LL * DD);
        float4 a0 = make_float4(0.f, 0.f, 0.f, 0.f);
        float4 a1 = make_float4(0.f, 0.f, 0.f, 0.f);
        for (int ws = 0; ws < LL / 64; ++ws) {     // 64 mask words
            unsigned long long w0 = mbits[0][ws];
            unsigned long long w1 = mbits[1][ws];
            #pragma unroll
            for (int ii = 0; ii < 4; ++ii) {
                int row = ws * 64 + ii * 16 + grp;
                float4 vv = v4[(size_t)row * (DD / 4) + sub];
                int sh = ii * 16 + grp;
                float m0 = (float)((w0 >> sh) & 1ULL);
                float m1 = (float)((w1 >> sh) & 1ULL);
                a0.x = fmaf(m0, vv.x, a0.x); a0.y = fmaf(m0, vv.y, a0.y);
                a0.z = fmaf(m0, vv.z, a0.z); a0.w = fmaf(m0, vv.w, a0.w);
                a1.x = fmaf(m1, vv.x, a1.x); a1.y = fmaf(m1, vv.y, a1.y);
                a1.z = fmaf(m1, vv.z, a1.z); a1.w = fmaf(m1, vv.w, a1.w);
            }
        }
        // fold 16 groups -> 8 in registers, then LDS
        if (grp >= 8) { redv4[grp - 8][0][sub] = a0; redv4[grp - 8][1][sub] = a1; }
        __syncthreads();
        if (grp < 8) {
            float4 o0 = redv4[grp][0][sub], o1 = redv4[grp][1][sub];
            a0.x += o0.x; a0.y += o0.y; a0.z += o0.z; a0.w += o0.w;
            a1.x += o1.x; a1.y += o1.y; a1.z += o1.z; a1.w += o1.w;
        }
        __syncthreads();
        if (grp < 8) { redv4[grp][0][sub] = a0; redv4[grp][1][sub] = a1; }
    }
    __syncthreads();
    if (t < QT * DD) {
        int qt = t >> 6, d = t & 63;
        float s = 0.f;
        #pragma unroll
        for (int g = 0; g < 8; ++g)
            s += reinterpret_cast<const float*>(&redv4[g][qt][d >> 2])[d & 3];
        int c = count_s[qt]; if (c < 1) c = 1;
        mean_s[qt][d] = s / (float)c;
    }
    __syncthreads();

    // ---- Phase C+D: per-wave top-32 tournament, softmax, gather -------------
    // Wave qt handles row qt. Lane owns 16 float4 groups: l4 = j*64 + lane.
    // Zero __syncthreads from here on.
    if (wave < QT) {
        const int qt = wave;
        const float4* sc4 = reinterpret_cast<const float4*>(&sc[qt][0]);

        float v1, v2; int i1, i2;
        auto scan2 = [&]() {
            v1 = -FLT_MAX; v2 = -FLT_MAX; i1 = 0x7fffffff; i2 = 0x7fffffff;
            for (int j = 0; j < 16; ++j) {
                float4 f = sc4[j * 64 + lane];
                int base = (j * 64 + lane) * 4;
                float vals[4] = { f.x, f.y, f.z, f.w };
                #pragma unroll
                for (int cpt = 0; cpt < 4; ++cpt) {
                    float val = vals[cpt]; int idx = base + cpt;
                    if (val > v1 || (val == v1 && idx < i1)) {
                        v2 = v1; i2 = i1; v1 = val; i1 = idx;
                    } else if (val > v2 || (val == v2 && idx < i2)) {
                        v2 = val; i2 = idx;
                    }
                }
            }
        };
        scan2();
        int nv = 2;                                // valid cached candidates
        float selv = -FLT_MAX; int seli = 0;       // lane s holds extraction s
        int S = KEEP;
        for (int s = 0; s < KEEP; ++s) {
            float m = v1; int mi = i1;
            #pragma unroll
            for (int off = 1; off < 64; off <<= 1) {
                float ov = __shfl_xor(m, off);
                int   oi = __shfl_xor(mi, off);
                if (ov > m || (ov == m && oi < mi)) { m = ov; mi = oi; }
            }
            if (m == -FLT_MAX) { S = s; break; }   // masked entries exhausted
            if (lane == s) { selv = m; seli = mi; }
            if (lane == ((mi >> 2) & 63)) {        // owner pops
                sc[qt][mi] = -FLT_MAX;
                if (nv == 2) { v1 = v2; i1 = i2; nv = 1; }
                else         { scan2(); nv = 2; }  // rare (~2% per lane)
            }
        }

        float o = mean_s[qt][lane];                // lane == output dim
        if (S > 0) {
            float mx = __shfl(selv, 0);            // extraction 0 is the max
            float e = (lane < S) ? expf(selv - mx) : 0.f;
            float ssum = e;
            #pragma unroll
            for (int off = 1; off < 64; off <<= 1) ssum += __shfl_xor(ssum, off);
            float w = e / ssum;
            for (int j = 0; j < S; ++j) {
                float wj = __shfl(w, j);
                int   ij = __shfl(seli, j);
                o += wj * vmat[((size_t)b * LL + ij) * DD + lane];
            }
        }
        out[(size_t)(n0 + qt) * DD + lane] = o;
    }
}

extern "C" void kernel_launch(void* const* d_in, const int* in_sizes, int n_in,
                              void* d_out, int out_size, void* d_ws, size_t ws_size,
                              hipStream_t stream) {
    const float* q    = (const float*)d_in[0];
    const float* kmat = (const float*)d_in[1];
    const float* vmat = (const float*)d_in[2];
    const int*   mask = (const int*)d_in[3];
    float* out = (float*)d_out;

    const int n_rows = NB * LQ;                // 4096
    dim3 grid(n_rows / QT), block(NT);
    hipLaunchKernelGGL(ga_fused, grid, block, 0, stream, q, kmat, vmat, mask, out);
}

// Round 3
// 1131.275 us; speedup vs baseline: 1.8340x; 1.8340x over previous
//
#include <hip/hip_runtime.h>
#include <float.h>
#include <math.h>

// Problem constants (from reference setup_inputs)
#define LQ   512
#define LL   4096      // key length
#define DD   64        // d_qk == d_v
#define KEEP 32        // MAX_SET_SIZE
#define NB   8         // batches
#define NROWS (NB * LQ)    // 4096 flat query rows

// ---- ws layout (floats) ----------------------------------------------------
#define WS_MEAN  (NROWS * LL)            // 16,777,216 : scores [row][l]
#define WS_CNT   (WS_MEAN + NROWS * DD)  // +262,144   : mean sums [row][d]
#define WS_TOTAL (WS_CNT + NROWS)        // +4,096     : counts [row]

// ============================================================================
// K0: zero the mean/count region (ws is poisoned 0xAA before every launch)
// ============================================================================
__global__ void k_zero(float* __restrict__ p, int n) {
    int i = blockIdx.x * blockDim.x + threadIdx.x;
    if (i < n) p[i] = 0.f;
}

// ============================================================================
// K1: masked scores -> ws, masked mean-sum/count -> ws (atomicAdd)
// Block = [32 q-rows] x [512 l-chunk], subtiles of 64 l.
// blockIdx = rt*8 + lc  => all 16 sharers of a (batch,lc) k/v chunk have
// blockIdx = lc (mod 8) => same XCD under round-robin dispatch (L2 reuse).
// ============================================================================
#define RT 32
#define LC 512
#define LS 64

__global__ __launch_bounds__(256) void k_scores_mean(
    const float* __restrict__ q,
    const float* __restrict__ kmat,
    const float* __restrict__ vmat,
    const int*   __restrict__ mask,
    float*       __restrict__ ws)
{
    __shared__ float4 Qs[RT * 16];            // [r][d4]     8 KB
    __shared__ float4 Ks[16 * LS];            // [d4][l]    16 KB (transposed)
    __shared__ float4 Vs[LS * 16];            // [l][d4]    16 KB (natural)
    __shared__ unsigned long long mb[RT];     // ballot word per row, per subtile

    float* ws_sc   = ws;
    float* ws_mean = ws + WS_MEAN;
    float* ws_cnt  = ws + WS_CNT;

    const int t    = threadIdx.x;
    const int wave = t >> 6;
    const int lane = t & 63;
    const int rt   = blockIdx.x >> 3;         // 0..127
    const int lc   = blockIdx.x & 7;          // 0..7
    const int n0   = rt * RT;                 // first flat query row
    const int b    = n0 / LQ;                 // batch (RT | LQ)
    const int lbase = lc * LC;

    // load Q tile once (512 float4, flat coalesced)
    {
        const float4* qg = reinterpret_cast<const float4*>(q) + (size_t)n0 * 16;
        Qs[t] = qg[t];
        Qs[t + 256] = qg[t + 256];
    }

    // mean accumulators: thread owns (rows 2*rg, 2*rg+1) x (dims d4*4..+3)
    const int d4 = lane & 15;
    const int rg = t >> 4;                    // 0..15
    float4 macc0 = make_float4(0.f, 0.f, 0.f, 0.f);
    float4 macc1 = make_float4(0.f, 0.f, 0.f, 0.f);
    float  creg  = 0.f;                       // lane p (0..7): count for row wave*8+p

    for (int s = 0; s < LC / LS; ++s) {
        const int l0 = lbase + s * LS;
        __syncthreads();                      // LDS reuse fence

        // stage K transposed: wave c writes Ks[(c*4+i)][lane] (consecutive-lane f4 = fast)
        {
            const float4* kg = reinterpret_cast<const float4*>(kmat)
                             + ((size_t)b * LL + l0 + lane) * 16;
            #pragma unroll
            for (int i = 0; i < 4; ++i)
                Ks[(wave * 4 + i) * LS + lane] = kg[wave * 4 + i];
        }
        // stage V natural: flat 1024-f4 copy (fully coalesced both sides)
        {
            const float4* vg = reinterpret_cast<const float4*>(vmat)
                             + ((size_t)b * LL + l0) * 16;
            #pragma unroll
            for (int i = 0; i < 4; ++i)
                Vs[t + 256 * i] = vg[t + 256 * i];
        }
        __syncthreads();

        // ---- score phase: lane = l, wave handles rows wave*8 .. wave*8+7 ----
        float acc[8];
        #pragma unroll
        for (int p = 0; p < 8; ++p) acc[p] = 0.f;
        #pragma unroll
        for (int dc = 0; dc < 16; ++dc) {
            float4 k4 = Ks[dc * LS + lane];
            #pragma unroll
            for (int p = 0; p < 8; ++p) {
                float4 q4 = Qs[(wave * 8 + p) * 16 + dc];   // wave-uniform broadcast
                acc[p] += k4.x * q4.x + k4.y * q4.y + k4.z * q4.z + k4.w * q4.w;
            }
        }
        #pragma unroll
        for (int p = 0; p < 8; ++p) {
            const int r = wave * 8 + p;
            int m = mask[(size_t)(n0 + r) * LL + l0 + lane];
            unsigned long long w = __ballot(m != 0);
            if (lane == 0) mb[r] = w;
            if (lane == p) creg += (float)__popcll(w);
            ws_sc[(size_t)(n0 + r) * LL + l0 + lane] = m ? acc[p] * 0.125f : -FLT_MAX;
        }
        __syncthreads();                      // mb visible to all

        // ---- mean phase: thread (rg, d4) accumulates rows 2rg, 2rg+1 --------
        {
            unsigned long long w0 = mb[2 * rg];
            unsigned long long w1 = mb[2 * rg + 1];
            #pragma unroll 16
            for (int l = 0; l < LS; ++l) {
                float4 v4 = Vs[l * 16 + d4];
                float m0 = (float)((w0 >> l) & 1ULL);
                float m1 = (float)((w1 >> l) & 1ULL);
                macc0.x = fmaf(m0, v4.x, macc0.x); macc0.y = fmaf(m0, v4.y, macc0.y);
                macc0.z = fmaf(m0, v4.z, macc0.z); macc0.w = fmaf(m0, v4.w, macc0.w);
                macc1.x = fmaf(m1, v4.x, macc1.x); macc1.y = fmaf(m1, v4.y, macc1.y);
                macc1.z = fmaf(m1, v4.z, macc1.z); macc1.w = fmaf(m1, v4.w, macc1.w);
            }
        }
    }

    // combine partial means/counts across the 8 l-chunk blocks
    {
        float* m0p = ws_mean + (size_t)(n0 + 2 * rg) * DD + d4 * 4;
        float* m1p = ws_mean + (size_t)(n0 + 2 * rg + 1) * DD + d4 * 4;
        atomicAdd(m0p + 0, macc0.x); atomicAdd(m0p + 1, macc0.y);
        atomicAdd(m0p + 2, macc0.z); atomicAdd(m0p + 3, macc0.w);
        atomicAdd(m1p + 0, macc1.x); atomicAdd(m1p + 1, macc1.y);
        atomicAdd(m1p + 2, macc1.z); atomicAdd(m1p + 3, macc1.w);
    }
    if (lane < 8) atomicAdd(&ws_cnt[n0 + wave * 8 + lane], creg);
}

// ============================================================================
// K2: per wave, tournament top-32 over one row's masked scores, softmax,
// v-gather, add mean, write out. 128 threads = 2 waves = 2 rows.
// ============================================================================
__global__ __launch_bounds__(128) void k_select(
    const float* __restrict__ vmat,
    const float* __restrict__ ws,
    float*       __restrict__ out)
{
    __shared__ float sc[2][LL];               // 32 KB

    const int t    = threadIdx.x;
    const int wave = t >> 6;
    const int lane = t & 63;
    const int row  = blockIdx.x * 2 + wave;
    const int b    = row / LQ;

    const float* ws_sc   = ws;
    const float* ws_mean = ws + WS_MEAN;
    const float* ws_cnt  = ws + WS_CNT;

    // load row scores to LDS (coalesced)
    {
        const float4* sg = reinterpret_cast<const float4*>(ws_sc) + (size_t)row * (LL / 4);
        float4* sl = reinterpret_cast<float4*>(&sc[wave][0]);
        #pragma unroll
        for (int i = 0; i < 16; ++i) sl[lane + 64 * i] = sg[lane + 64 * i];
    }
    __syncthreads();

    const float4* sc4 = reinterpret_cast<const float4*>(&sc[wave][0]);

    float v1, v2; int i1, i2;
    auto scan2 = [&]() {
        v1 = -FLT_MAX; v2 = -FLT_MAX; i1 = 0x7fffffff; i2 = 0x7fffffff;
        for (int j = 0; j < 16; ++j) {
            float4 f = sc4[j * 64 + lane];
            int base = (j * 64 + lane) * 4;
            float vals[4] = { f.x, f.y, f.z, f.w };
            #pragma unroll
            for (int cpt = 0; cpt < 4; ++cpt) {
                float val = vals[cpt]; int idx = base + cpt;
                if (val > v1 || (val == v1 && idx < i1)) {
                    v2 = v1; i2 = i1; v1 = val; i1 = idx;
                } else if (val > v2 || (val == v2 && idx < i2)) {
                    v2 = val; i2 = idx;
                }
            }
        }
    };
    scan2();
    int nv = 2;
    float selv = -FLT_MAX; int seli = 0;      // lane s holds extraction s
    int S = KEEP;
    for (int s = 0; s < KEEP; ++s) {
        float m = v1; int mi = i1;
        #pragma unroll
        for (int off = 1; off < 64; off <<= 1) {
            float ov = __shfl_xor(m, off);
            int   oi = __shfl_xor(mi, off);
            if (ov > m || (ov == m && oi < mi)) { m = ov; mi = oi; }
        }
        if (m == -FLT_MAX) { S = s; break; }  // masked entries exhausted
        if (lane == s) { selv = m; seli = mi; }
        if (lane == ((mi >> 2) & 63)) {       // owner pops
            sc[wave][mi] = -FLT_MAX;
            if (nv == 2) { v1 = v2; i1 = i2; nv = 1; }
            else         { scan2(); nv = 2; } // rare
        }
    }

    float cnt = ws_cnt[row]; if (cnt < 1.f) cnt = 1.f;
    float o = ws_mean[(size_t)row * DD + lane] / cnt;
    if (S > 0) {
        float mx = __shfl(selv, 0);           // extraction 0 is the max
        float e = (lane < S) ? expf(selv - mx) : 0.f;
        float ssum = e;
        #pragma unroll
        for (int off = 1; off < 64; off <<= 1) ssum += __shfl_xor(ssum, off);
        float w = e / ssum;
        for (int j = 0; j < S; ++j) {
            float wj = __shfl(w, j);
            int   ij = __shfl(seli, j);
            o += wj * vmat[((size_t)b * LL + ij) * DD + lane];
        }
    }
    out[(size_t)row * DD + lane] = o;
}

// ============================================================================
// Fallback (proven round-1 kernel) in case ws_size < WS_TOTAL*4.
// ============================================================================
#define QT   2
#define NT   256
#define NTILES (LL / NT)

__global__ __launch_bounds__(NT, 4) void ga_fused_fb(
    const float* __restrict__ q, const float* __restrict__ kmat,
    const float* __restrict__ vmat, const int* __restrict__ mask,
    float* __restrict__ out)
{
    __shared__ float sc[QT][LL];
    __shared__ float q_s[QT][DD];
    __shared__ unsigned long long mbits[QT][LL / 64];
    __shared__ float redv[4][QT][DD];
    __shared__ float mean_s[QT][DD];
    __shared__ int   count_s[QT];
    __shared__ int   sel_idx[QT][KEEP];
    __shared__ float sel_val[QT][KEEP];
    __shared__ int   sel_cnt[QT];
    __shared__ float wred[4];
    __shared__ int   ired[4];
    __shared__ int   brk;
    __shared__ float wgt[QT][KEEP];

    const int t = threadIdx.x, wave = t >> 6, lane = t & 63;
    const int n0 = blockIdx.x * QT, b = n0 / LQ;

    if (t < QT) sel_cnt[t] = 0;
    if (t < QT * DD) q_s[t >> 6][t & 63] = q[(size_t)(n0 + (t >> 6)) * DD + (t & 63)];
    __syncthreads();

    const float4* q4_0 = reinterpret_cast<const float4*>(&q_s[0][0]);
    const float4* q4_1 = reinterpret_cast<const float4*>(&q_s[1][0]);
    for (int tile = 0; tile < NTILES; ++tile) {
        int l = tile * NT + t;
        const float4* kr = reinterpret_cast<const float4*>(kmat + (size_t)(b * LL + l) * DD);
        float d0 = 0.f, d1 = 0.f;
        #pragma unroll
        for (int i = 0; i < 16; ++i) {
            float4 kk = kr[i], qa = q4_0[i], qb = q4_1[i];
            d0 += kk.x * qa.x + kk.y * qa.y + kk.z * qa.z + kk.w * qa.w;
            d1 += kk.x * qb.x + kk.y * qb.y + kk.z * qb.z + kk.w * qb.w;
        }
        int mv0 = mask[(size_t)n0 * LL + l];
        int mv1 = mask[(size_t)(n0 + 1) * LL + l];
        unsigned long long b0 = __ballot(mv0 != 0);
        unsigned long long b1 = __ballot(mv1 != 0);
        if (lane == 0) { mbits[0][tile * 4 + wave] = b0; mbits[1][tile * 4 + wave] = b1; }
        sc[0][l] = mv0 ? d0 * 0.125f : -FLT_MAX;
        sc[1][l] = mv1 ? d1 * 0.125f : -FLT_MAX;
    }
    __syncthreads();

    if (wave < QT) {
        int c = (int)__popcll(mbits[wave][lane]);
        for (int off = 32; off >= 1; off >>= 1) c += __shfl_down(c, off);
        if (lane == 0) count_s[wave] = c;
    }
    {
        float acc0 = 0.f, acc1 = 0.f;
        const int g = wave, d = lane;
        for (int wi = 0; wi < LL / 64; ++wi) {
            unsigned long long w0 = mbits[0][wi], w1 = mbits[1][wi];
            const float* vp = vmat + (size_t)(b * LL + wi * 64 + g) * DD + d;
            #pragma unroll 4
            for (int ii = 0; ii < 16; ++ii) {
                int sh = g + 4 * ii;
                float vv = vp[(size_t)(4 * ii) * DD];
                if ((w0 >> sh) & 1ULL) acc0 += vv;
                if ((w1 >> sh) & 1ULL) acc1 += vv;
            }
        }
        redv[g][0][d] = acc0; redv[g][1][d] = acc1;
    }
    __syncthreads();
    if (t < QT * DD) {
        int qt = t >> 6, dd = t & 63;
        float s2 = redv[0][qt][dd] + redv[1][qt][dd] + redv[2][qt][dd] + redv[3][qt][dd];
        int c = count_s[qt]; if (c < 1) c = 1;
        mean_s[qt][dd] = s2 / (float)c;
    }
    __syncthreads();

    for (int qt = 0; qt < QT; ++qt) {
        for (int s = 0; s < KEEP; ++s) {
            float m = -FLT_MAX; int mi = LL;
            for (int j = 0; j < NTILES; ++j) {
                int l = j * NT + t;
                float val = sc[qt][l];
                if (val > m) { m = val; mi = l; }
            }
            for (int off = 32; off >= 1; off >>= 1) {
                float ov = __shfl_down(m, off);
                int   oi = __shfl_down(mi, off);
                if (ov > m || (ov == m && oi < mi)) { m = ov; mi = oi; }
            }
            if (lane == 0) { wred[wave] = m; ired[wave] = mi; }
            __syncthreads();
            if (t == 0) {
                float bv = wred[0]; int bi = ired[0];
                for (int w2 = 1; w2 < 4; ++w2) {
                    float ov = wred[w2]; int oi = ired[w2];
                    if (ov > bv || (ov == bv && oi < bi)) { bv = ov; bi = oi; }
                }
                if (bv > -FLT_MAX) {
                    sel_idx[qt][s] = bi; sel_val[qt][s] = bv; sel_cnt[qt] = s + 1;
                    sc[qt][bi] = -FLT_MAX; brk = 0;
                } else brk = 1;
            }
            __syncthreads();
            if (brk) break;
        }
    }

    if (wave < QT) {
        int qt = wave, S = sel_cnt[qt];
        if (S > 0) {
            float mx = sel_val[qt][0];
            float e = 0.f;
            if (lane < S) e = expf(sel_val[qt][lane] - mx);
            float ssum = e;
            for (int off = 32; off >= 1; off >>= 1) ssum += __shfl_xor(ssum, off);
            if (lane < S) wgt[qt][lane] = e / ssum;
        }
    }
    __syncthreads();
    if (wave < QT) {
        int qt = wave, S = sel_cnt[qt];
        float o = mean_s[qt][lane];
        for (int j = 0; j < S; ++j)
            o += wgt[qt][j] * vmat[(size_t)(b * LL + sel_idx[qt][j]) * DD + lane];
        out[(size_t)(n0 + qt) * DD + lane] = o;
    }
}

// ============================================================================
extern "C" void kernel_launch(void* const* d_in, const int* in_sizes, int n_in,
                              void* d_out, int out_size, void* d_ws, size_t ws_size,
                              hipStream_t stream) {
    const float* q    = (const float*)d_in[0];
    const float* kmat = (const float*)d_in[1];
    const float* vmat = (const float*)d_in[2];
    const int*   mask = (const int*)d_in[3];
    float* out = (float*)d_out;

    const size_t need = (size_t)WS_TOTAL * sizeof(float);   // ~68.2 MB
    if (ws_size >= need) {
        float* ws = (float*)d_ws;
        const int nz = NROWS * DD + NROWS;
        hipLaunchKernelGGL(k_zero, dim3((nz + 255) / 256), dim3(256), 0, stream,
                           ws + WS_MEAN, nz);
        hipLaunchKernelGGL(k_scores_mean, dim3(128 * 8), dim3(256), 0, stream,
                           q, kmat, vmat, mask, ws);
        hipLaunchKernelGGL(k_select, dim3(NROWS / 2), dim3(128), 0, stream,
                           vmat, ws, out);
    } else {
        hipLaunchKernelGGL(ga_fused_fb, dim3(NROWS / QT), dim3(NT), 0, stream,
                           q, kmat, vmat, mask, out);
    }
}

// Round 4
// 651.855 us; speedup vs baseline: 3.1829x; 1.7355x over previous
//
#include <hip/hip_runtime.h>
#include <float.h>
#include <math.h>

// Problem constants (from reference setup_inputs)
#define LQ   512
#define LL   4096      // key length
#define DD   64        // d_qk == d_v
#define KEEP 32        // MAX_SET_SIZE
#define NB   8         // batches
#define NROWS (NB * LQ)    // 4096 flat query rows

// K1 tiling
#define RT   32            // query rows per block
#define NLC  4             // l-chunks (partials per row)
#define LC   (LL / NLC)    // 1024
#define LS   64            // l-subtile staged in LDS
#define NSUB (LC / LS)     // 16

// ---- ws layout (floats) ----------------------------------------------------
// scores : [NROWS][LL]                      64 MB
// meanp  : [NROWS/RT][NLC][RT][DD]           4 MB   (per-block mean partial)
// cntp   : [NROWS/RT][NLC][RT]              64 KB   (per-block count partial)
#define MEANP_SZ ((NROWS / RT) * NLC * RT * DD)
#define CNTP_SZ  ((NROWS / RT) * NLC * RT)
#define WS_MEANP (NROWS * LL)
#define WS_CNTP  (WS_MEANP + MEANP_SZ)
#define WS_TOTAL (WS_CNTP + CNTP_SZ)        // 17,842,176 floats = 71.4 MB

// ============================================================================
// K1: masked scores -> ws; per-block mean/count partials -> ws (no atomics).
// Block = [32 q-rows] x [1024 l-chunk], subtiles of 64 l.
// __launch_bounds__(256,3): occupancy is LDS-capped at 3 blocks/CU, so the
// ~170-VGPR cap is free insurance against the spills that killed rounds 2-3.
// ============================================================================
__global__ __launch_bounds__(256, 3) void k_scores_mean(
    const float* __restrict__ q,
    const float* __restrict__ kmat,
    const float* __restrict__ vmat,
    const int*   __restrict__ mask,
    float*       __restrict__ ws)
{
    __shared__ float4 Qs[RT * 16];            // [r][d4]     8 KB
    __shared__ float4 Ks[16 * LS];            // [d4][l]    16 KB (transposed)
    __shared__ float4 Vs[LS * 16];            // [l][d4]    16 KB (natural)
    __shared__ unsigned long long mb[RT];     // ballot word per row, per subtile

    float* ws_sc    = ws;
    float* ws_meanp = ws + WS_MEANP;
    float* ws_cntp  = ws + WS_CNTP;

    const int t    = threadIdx.x;
    const int wave = t >> 6;
    const int lane = t & 63;
    const int rt   = blockIdx.x >> 2;         // 0..127  (blockIdx / NLC)
    const int lc   = blockIdx.x & (NLC - 1);  // 0..3
    const int n0   = rt * RT;                 // first flat query row
    const int b    = n0 / LQ;                 // batch (RT | LQ)
    const int lbase = lc * LC;

    // load Q tile once (512 float4, flat coalesced)
    {
        const float4* qg = reinterpret_cast<const float4*>(q) + (size_t)n0 * 16;
        Qs[t] = qg[t];
        Qs[t + 256] = qg[t + 256];
    }

    // mean accumulators: thread (rg = t>>4, d4 = t&15) owns rows 2rg,2rg+1,
    // dims d4*4..d4*4+3
    const int d4 = t & 15;
    const int rg = t >> 4;
    float4 macc0 = make_float4(0.f, 0.f, 0.f, 0.f);
    float4 macc1 = make_float4(0.f, 0.f, 0.f, 0.f);
    float  creg  = 0.f;                       // lane p<8: count for row wave*8+p

    for (int s = 0; s < NSUB; ++s) {
        const int l0 = lbase + s * LS;
        __syncthreads();                      // LDS reuse fence

        // stage K transposed: wave c writes Ks[(c*4+i)][lane]
        {
            const float4* kg = reinterpret_cast<const float4*>(kmat)
                             + ((size_t)b * LL + l0 + lane) * 16;
            #pragma unroll
            for (int i = 0; i < 4; ++i)
                Ks[(wave * 4 + i) * LS + lane] = kg[wave * 4 + i];
        }
        // stage V natural: flat 1024-f4 copy
        {
            const float4* vg = reinterpret_cast<const float4*>(vmat)
                             + ((size_t)b * LL + l0) * 16;
            #pragma unroll
            for (int i = 0; i < 4; ++i)
                Vs[t + 256 * i] = vg[t + 256 * i];
        }
        __syncthreads();

        // ---- score phase: lane = l, wave handles rows wave*8 .. wave*8+7 ----
        float acc[8];
        #pragma unroll
        for (int p = 0; p < 8; ++p) acc[p] = 0.f;
        #pragma unroll 4
        for (int dc = 0; dc < 16; ++dc) {
            float4 k4 = Ks[dc * LS + lane];
            #pragma unroll
            for (int p = 0; p < 8; ++p) {
                float4 q4 = Qs[(wave * 8 + p) * 16 + dc];   // wave-uniform broadcast
                acc[p] = fmaf(k4.x, q4.x,
                         fmaf(k4.y, q4.y,
                         fmaf(k4.z, q4.z,
                         fmaf(k4.w, q4.w, acc[p]))));
            }
        }
        #pragma unroll
        for (int p = 0; p < 8; ++p) {
            const int r = wave * 8 + p;
            int m = mask[(size_t)(n0 + r) * LL + l0 + lane];
            unsigned long long w = __ballot(m != 0);
            if (lane == 0) mb[r] = w;
            if (lane == p) creg += (float)__popcll(w);
            ws_sc[(size_t)(n0 + r) * LL + l0 + lane] = m ? acc[p] * 0.125f : -FLT_MAX;
        }
        __syncthreads();                      // mb visible to all

        // ---- mean phase: thread (rg, d4) accumulates rows 2rg, 2rg+1 --------
        {
            unsigned long long w0 = mb[2 * rg];
            unsigned long long w1 = mb[2 * rg + 1];
            #pragma unroll 4
            for (int l = 0; l < LS; ++l) {
                float4 v4 = Vs[l * 16 + d4];
                float m0 = (float)((w0 >> l) & 1ULL);
                float m1 = (float)((w1 >> l) & 1ULL);
                macc0.x = fmaf(m0, v4.x, macc0.x); macc0.y = fmaf(m0, v4.y, macc0.y);
                macc0.z = fmaf(m0, v4.z, macc0.z); macc0.w = fmaf(m0, v4.w, macc0.w);
                macc1.x = fmaf(m1, v4.x, macc1.x); macc1.y = fmaf(m1, v4.y, macc1.y);
                macc1.z = fmaf(m1, v4.z, macc1.z); macc1.w = fmaf(m1, v4.w, macc1.w);
            }
        }
    }

    // ---- write private partials (fully overwritten -> no init needed) -------
    {
        float4* mp = reinterpret_cast<float4*>(
            ws_meanp + (((size_t)rt * NLC + lc) * RT) * DD);
        mp[(2 * rg)     * 16 + d4] = macc0;
        mp[(2 * rg + 1) * 16 + d4] = macc1;
    }
    if (lane < 8)
        ws_cntp[((size_t)rt * NLC + lc) * RT + wave * 8 + lane] = creg;
}

// ============================================================================
// K2: per wave, tournament top-32 over one row's masked scores, softmax,
// v-gather, reduce mean partials, write out. 128 threads = 2 waves = 2 rows.
// ============================================================================
__global__ __launch_bounds__(128, 2) void k_select(
    const float* __restrict__ vmat,
    const float* __restrict__ ws,
    float*       __restrict__ out)
{
    __shared__ float sc[2][LL];               // 32 KB

    const int t    = threadIdx.x;
    const int wave = t >> 6;
    const int lane = t & 63;
    const int row  = blockIdx.x * 2 + wave;
    const int b    = row / LQ;

    const float* ws_sc    = ws;
    const float* ws_meanp = ws + WS_MEANP;
    const float* ws_cntp  = ws + WS_CNTP;

    // load row scores to LDS (coalesced)
    {
        const float4* sg = reinterpret_cast<const float4*>(ws_sc) + (size_t)row * (LL / 4);
        float4* sl = reinterpret_cast<float4*>(&sc[wave][0]);
        #pragma unroll
        for (int i = 0; i < 16; ++i) sl[lane + 64 * i] = sg[lane + 64 * i];
    }
    __syncthreads();

    const float4* sc4 = reinterpret_cast<const float4*>(&sc[wave][0]);

    float v1, v2; int i1, i2;
    auto scan2 = [&]() {
        v1 = -FLT_MAX; v2 = -FLT_MAX; i1 = 0x7fffffff; i2 = 0x7fffffff;
        for (int j = 0; j < 16; ++j) {
            float4 f = sc4[j * 64 + lane];
            int base = (j * 64 + lane) * 4;
            float vals[4] = { f.x, f.y, f.z, f.w };
            #pragma unroll
            for (int cpt = 0; cpt < 4; ++cpt) {
                float val = vals[cpt]; int idx = base + cpt;
                if (val > v1 || (val == v1 && idx < i1)) {
                    v2 = v1; i2 = i1; v1 = val; i1 = idx;
                } else if (val > v2 || (val == v2 && idx < i2)) {
                    v2 = val; i2 = idx;
                }
            }
        }
    };
    scan2();
    int nv = 2;
    float selv = -FLT_MAX; int seli = 0;      // lane s holds extraction s
    int S = KEEP;
    for (int s = 0; s < KEEP; ++s) {
        float m = v1; int mi = i1;
        #pragma unroll
        for (int off = 1; off < 64; off <<= 1) {
            float ov = __shfl_xor(m, off);
            int   oi = __shfl_xor(mi, off);
            if (ov > m || (ov == m && oi < mi)) { m = ov; mi = oi; }
        }
        if (m == -FLT_MAX) { S = s; break; }  // masked entries exhausted
        if (lane == s) { selv = m; seli = mi; }
        if (lane == ((mi >> 2) & 63)) {       // owner pops
            sc[wave][mi] = -FLT_MAX;
            if (nv == 2) { v1 = v2; i1 = i2; nv = 1; }
            else         { scan2(); nv = 2; } // rare
        }
    }

    // ---- reduce mean/count partials over the NLC l-chunk blocks -------------
    const int rt = row >> 5;                  // row / RT
    const int r  = row & (RT - 1);
    float o = 0.f;
    #pragma unroll
    for (int lc = 0; lc < NLC; ++lc)
        o += ws_meanp[(((size_t)rt * NLC + lc) * RT + r) * DD + lane];
    float cnt = 0.f;
    #pragma unroll
    for (int lc = 0; lc < NLC; ++lc)
        cnt += ws_cntp[((size_t)rt * NLC + lc) * RT + r];
    if (cnt < 1.f) cnt = 1.f;
    o /= cnt;

    if (S > 0) {
        float mx = __shfl(selv, 0);           // extraction 0 is the max
        float e = (lane < S) ? expf(selv - mx) : 0.f;
        float ssum = e;
        #pragma unroll
        for (int off = 1; off < 64; off <<= 1) ssum += __shfl_xor(ssum, off);
        float w = e / ssum;
        for (int j = 0; j < S; ++j) {
            float wj = __shfl(w, j);
            int   ij = __shfl(seli, j);
            o += wj * vmat[((size_t)b * LL + ij) * DD + lane];
        }
    }
    out[(size_t)row * DD + lane] = o;
}

// ============================================================================
// Fallback (proven round-1 monolith) in case ws_size < WS_TOTAL*4.
// ============================================================================
#define QT   2
#define NT   256
#define NTILES (LL / NT)

__global__ __launch_bounds__(NT, 4) void ga_fused_fb(
    const float* __restrict__ q, const float* __restrict__ kmat,
    const float* __restrict__ vmat, const int* __restrict__ mask,
    float* __restrict__ out)
{
    __shared__ float sc[QT][LL];
    __shared__ float q_s[QT][DD];
    __shared__ unsigned long long mbits[QT][LL / 64];
    __shared__ float redv[4][QT][DD];
    __shared__ float mean_s[QT][DD];
    __shared__ int   count_s[QT];
    __shared__ int   sel_idx[QT][KEEP];
    __shared__ float sel_val[QT][KEEP];
    __shared__ int   sel_cnt[QT];
    __shared__ float wred[4];
    __shared__ int   ired[4];
    __shared__ int   brk;
    __shared__ float wgt[QT][KEEP];

    const int t = threadIdx.x, wave = t >> 6, lane = t & 63;
    const int n0 = blockIdx.x * QT, b = n0 / LQ;

    if (t < QT) sel_cnt[t] = 0;
    if (t < QT * DD) q_s[t >> 6][t & 63] = q[(size_t)(n0 + (t >> 6)) * DD + (t & 63)];
    __syncthreads();

    const float4* q4_0 = reinterpret_cast<const float4*>(&q_s[0][0]);
    const float4* q4_1 = reinterpret_cast<const float4*>(&q_s[1][0]);
    for (int tile = 0; tile < NTILES; ++tile) {
        int l = tile * NT + t;
        const float4* kr = reinterpret_cast<const float4*>(kmat + (size_t)(b * LL + l) * DD);
        float d0 = 0.f, d1 = 0.f;
        #pragma unroll
        for (int i = 0; i < 16; ++i) {
            float4 kk = kr[i], qa = q4_0[i], qb = q4_1[i];
            d0 += kk.x * qa.x + kk.y * qa.y + kk.z * qa.z + kk.w * qa.w;
            d1 += kk.x * qb.x + kk.y * qb.y + kk.z * qb.z + kk.w * qb.w;
        }
        int mv0 = mask[(size_t)n0 * LL + l];
        int mv1 = mask[(size_t)(n0 + 1) * LL + l];
        unsigned long long b0 = __ballot(mv0 != 0);
        unsigned long long b1 = __ballot(mv1 != 0);
        if (lane == 0) { mbits[0][tile * 4 + wave] = b0; mbits[1][tile * 4 + wave] = b1; }
        sc[0][l] = mv0 ? d0 * 0.125f : -FLT_MAX;
        sc[1][l] = mv1 ? d1 * 0.125f : -FLT_MAX;
    }
    __syncthreads();

    if (wave < QT) {
        int c = (int)__popcll(mbits[wave][lane]);
        for (int off = 32; off >= 1; off >>= 1) c += __shfl_down(c, off);
        if (lane == 0) count_s[wave] = c;
    }
    {
        float acc0 = 0.f, acc1 = 0.f;
        const int g = wave, d = lane;
        for (int wi = 0; wi < LL / 64; ++wi) {
            unsigned long long w0 = mbits[0][wi], w1 = mbits[1][wi];
            const float* vp = vmat + (size_t)(b * LL + wi * 64 + g) * DD + d;
            #pragma unroll 4
            for (int ii = 0; ii < 16; ++ii) {
                int sh = g + 4 * ii;
                float vv = vp[(size_t)(4 * ii) * DD];
                if ((w0 >> sh) & 1ULL) acc0 += vv;
                if ((w1 >> sh) & 1ULL) acc1 += vv;
            }
        }
        redv[g][0][d] = acc0; redv[g][1][d] = acc1;
    }
    __syncthreads();
    if (t < QT * DD) {
        int qt = t >> 6, dd = t & 63;
        float s2 = redv[0][qt][dd] + redv[1][qt][dd] + redv[2][qt][dd] + redv[3][qt][dd];
        int c = count_s[qt]; if (c < 1) c = 1;
        mean_s[qt][dd] = s2 / (float)c;
    }
    __syncthreads();

    for (int qt = 0; qt < QT; ++qt) {
        for (int s = 0; s < KEEP; ++s) {
            float m = -FLT_MAX; int mi = LL;
            for (int j = 0; j < NTILES; ++j) {
                int l = j * NT + t;
                float val = sc[qt][l];
                if (val > m) { m = val; mi = l; }
            }
            for (int off = 32; off >= 1; off >>= 1) {
                float ov = __shfl_down(m, off);
                int   oi = __shfl_down(mi, off);
                if (ov > m || (ov == m && oi < mi)) { m = ov; mi = oi; }
            }
            if (lane == 0) { wred[wave] = m; ired[wave] = mi; }
            __syncthreads();
            if (t == 0) {
                float bv = wred[0]; int bi = ired[0];
                for (int w2 = 1; w2 < 4; ++w2) {
                    float ov = wred[w2]; int oi = ired[w2];
                    if (ov > bv || (ov == bv && oi < bi)) { bv = ov; bi = oi; }
                }
                if (bv > -FLT_MAX) {
                    sel_idx[qt][s] = bi; sel_val[qt][s] = bv; sel_cnt[qt] = s + 1;
                    sc[qt][bi] = -FLT_MAX; brk = 0;
                } else brk = 1;
            }
            __syncthreads();
            if (brk) break;
        }
    }

    if (wave < QT) {
        int qt = wave, S = sel_cnt[qt];
        if (S > 0) {
            float mx = sel_val[qt][0];
            float e = 0.f;
            if (lane < S) e = expf(sel_val[qt][lane] - mx);
            float ssum = e;
            for (int off = 32; off >= 1; off >>= 1) ssum += __shfl_xor(ssum, off);
            if (lane < S) wgt[qt][lane] = e / ssum;
        }
    }
    __syncthreads();
    if (wave < QT) {
        int qt = wave, S = sel_cnt[qt];
        float o = mean_s[qt][lane];
        for (int j = 0; j < S; ++j)
            o += wgt[qt][j] * vmat[(size_t)(b * LL + sel_idx[qt][j]) * DD + lane];
        out[(size_t)(n0 + qt) * DD + lane] = o;
    }
}

// ============================================================================
extern "C" void kernel_launch(void* const* d_in, const int* in_sizes, int n_in,
                              void* d_out, int out_size, void* d_ws, size_t ws_size,
                              hipStream_t stream) {
    const float* q    = (const float*)d_in[0];
    const float* kmat = (const float*)d_in[1];
    const float* vmat = (const float*)d_in[2];
    const int*   mask = (const int*)d_in[3];
    float* out = (float*)d_out;

    const size_t need = (size_t)WS_TOTAL * sizeof(float);   // ~71.4 MB
    if (ws_size >= need) {
        float* ws = (float*)d_ws;
        hipLaunchKernelGGL(k_scores_mean, dim3((NROWS / RT) * NLC), dim3(256),
                           0, stream, q, kmat, vmat, mask, ws);
        hipLaunchKernelGGL(k_select, dim3(NROWS / 2), dim3(128), 0, stream,
                           vmat, ws, out);
    } else {
        hipLaunchKernelGGL(ga_fused_fb, dim3(NROWS / QT), dim3(NT), 0, stream,
                           q, kmat, vmat, mask, out);
    }
}

// Round 5
// 603.076 us; speedup vs baseline: 3.4403x; 1.0809x over previous
//
#include <hip/hip_runtime.h>
#include <float.h>
#include <math.h>

// Problem constants (from reference setup_inputs)
#define LQ   512
#define LL   4096      // key length
#define DD   64        // d_qk == d_v
#define KEEP 32        // MAX_SET_SIZE
#define NB   8         // batches
#define NROWS (NB * LQ)    // 4096 flat query rows

// K1 tiling
#define RT    32           // query rows per block
#define NLC   4            // l-chunks (partials per row)
#define LC    (LL / NLC)   // 1024
#define LSP   128          // l's per staging round
#define NPAIR (LC / LSP)   // 8

// ---- ws layout (floats) ----------------------------------------------------
#define MEANP_SZ ((NROWS / RT) * NLC * RT * DD)
#define CNTP_SZ  ((NROWS / RT) * NLC * RT)
#define WS_MEANP (NROWS * LL)
#define WS_CNTP  (WS_MEANP + MEANP_SZ)
#define WS_TOTAL (WS_CNTP + CNTP_SZ)        // 71.4 MB (proven available in R4)

#define MASKED_KEY 0x00800000u              // order-key of -FLT_MAX

__device__ __forceinline__ float dot4(float4 a, float4 b) {
    return a.x * b.x + a.y * b.y + a.z * b.z + a.w * b.w;
}

// ============================================================================
// K1: masked scores -> ws; per-block mean/count partials -> ws (no atomics).
// Block = [32 q-rows] x [1024 l-chunk], staged 128 l at a time.
// q read through readfirstlane-uniform pointers -> s_load (off the LDS pipe).
// ============================================================================
__global__ __launch_bounds__(256, 4) void k_scores_mean(
    const float* __restrict__ q,
    const float* __restrict__ kmat,
    const float* __restrict__ vmat,
    const int*   __restrict__ mask,
    float*       __restrict__ ws)
{
    __shared__ float4 Ss4[16 * LSP];              // 32 KB: K^T [dc][l], reused for V
    __shared__ unsigned long long mb[RT][2];      // ballot words per row (this pair)

    float* ws_sc    = ws;
    float* ws_meanp = ws + WS_MEANP;
    float* ws_cntp  = ws + WS_CNTP;

    const int t    = threadIdx.x;
    const int wave = t >> 6;
    const int lane = t & 63;
    const int rt   = blockIdx.x >> 2;             // 0..127
    const int lc   = blockIdx.x & (NLC - 1);      // 0..3
    const int n0   = rt * RT;
    const int b    = n0 / LQ;
    const int lbase = lc * LC;

    // wave-uniform q-row byte bases -> SGPRs
    int qbase[8];
    #pragma unroll
    for (int p = 0; p < 8; ++p)
        qbase[p] = __builtin_amdgcn_readfirstlane((n0 + wave * 8 + p) * DD);

    // mean mapping: thread (rg = t>>5, dg = t&31) owns rows 4rg..4rg+3, dims 2dg..2dg+1
    const int dg = t & 31;
    const int rg = t >> 5;
    float2 macc[4];
    #pragma unroll
    for (int j = 0; j < 4; ++j) macc[j] = make_float2(0.f, 0.f);
    float creg = 0.f;                             // lane p<8: count for row wave*8+p

    const float4* kg = reinterpret_cast<const float4*>(kmat) + (size_t)b * LL * 16;
    const float4* vg = reinterpret_cast<const float4*>(vmat) + (size_t)b * LL * 16;
    float2* Vs2 = reinterpret_cast<float2*>(Ss4);

    for (int s = 0; s < NPAIR; ++s) {
        const int l0 = lbase + s * LSP;
        __syncthreads();                          // Ss free (prev mean done)

        // stage K transposed: wave w covers dc = w*4..w*4+3 (proven 0-conflict)
        #pragma unroll
        for (int i = 0; i < 2; ++i)
            #pragma unroll
            for (int j = 0; j < 4; ++j)
                Ss4[(wave * 4 + j) * LSP + lane + 64 * i] =
                    kg[(size_t)(l0 + lane + 64 * i) * 16 + wave * 4 + j];

        // mask prefetch (16 independent coalesced loads)
        int mr0[8], mr1[8];
        #pragma unroll
        for (int p = 0; p < 8; ++p) {
            const int r = wave * 8 + p;
            mr0[p] = mask[(size_t)(n0 + r) * LL + l0 + lane];
            mr1[p] = mask[(size_t)(n0 + r) * LL + l0 + 64 + lane];
        }
        __syncthreads();

        // ---- scores: lane = l (two halves), wave rows wave*8..+7 ------------
        float acc0[8], acc1[8];
        #pragma unroll
        for (int p = 0; p < 8; ++p) { acc0[p] = 0.f; acc1[p] = 0.f; }
        #pragma unroll
        for (int dc = 0; dc < 16; ++dc) {
            float4 ka = Ss4[dc * LSP + lane];
            float4 kb = Ss4[dc * LSP + 64 + lane];
            #pragma unroll
            for (int p = 0; p < 8; ++p) {
                float4 q4 = *reinterpret_cast<const float4*>(q + qbase[p] + dc * 4);
                acc0[p] += dot4(ka, q4);
                acc1[p] += dot4(kb, q4);
            }
        }
        #pragma unroll
        for (int p = 0; p < 8; ++p) {
            const int r = wave * 8 + p;
            unsigned long long b0 = __ballot(mr0[p] != 0);
            unsigned long long b1 = __ballot(mr1[p] != 0);
            if (lane == 0) { mb[r][0] = b0; mb[r][1] = b1; }
            if (lane == p) creg += (float)(__popcll(b0) + __popcll(b1));
            ws_sc[(size_t)(n0 + r) * LL + l0 + lane]      = mr0[p] ? acc0[p] * 0.125f : -FLT_MAX;
            ws_sc[(size_t)(n0 + r) * LL + l0 + 64 + lane] = mr1[p] ? acc1[p] * 0.125f : -FLT_MAX;
        }
        __syncthreads();                          // K reads done; mb visible

        // stage V natural (flat coalesced copy, 32 KB)
        #pragma unroll
        for (int i = 0; i < 8; ++i)
            Ss4[t + 256 * i] = vg[(size_t)l0 * 16 + t + 256 * i];
        __syncthreads();

        // ---- mean: thread (rg,dg), rows 4rg..+3, dims 2dg..+1, b64 reads ----
        #pragma unroll
        for (int lw = 0; lw < 2; ++lw) {
            unsigned long long w0 = mb[4 * rg + 0][lw];
            unsigned long long w1 = mb[4 * rg + 1][lw];
            unsigned long long w2 = mb[4 * rg + 2][lw];
            unsigned long long w3 = mb[4 * rg + 3][lw];
            #pragma unroll 8
            for (int l6 = 0; l6 < 64; ++l6) {
                float2 v2 = Vs2[(lw * 64 + l6) * 32 + dg];
                float m0 = (float)((w0 >> l6) & 1ULL);
                float m1 = (float)((w1 >> l6) & 1ULL);
                float m2 = (float)((w2 >> l6) & 1ULL);
                float m3 = (float)((w3 >> l6) & 1ULL);
                macc[0].x = fmaf(m0, v2.x, macc[0].x); macc[0].y = fmaf(m0, v2.y, macc[0].y);
                macc[1].x = fmaf(m1, v2.x, macc[1].x); macc[1].y = fmaf(m1, v2.y, macc[1].y);
                macc[2].x = fmaf(m2, v2.x, macc[2].x); macc[2].y = fmaf(m2, v2.y, macc[2].y);
                macc[3].x = fmaf(m3, v2.x, macc[3].x); macc[3].y = fmaf(m3, v2.y, macc[3].y);
            }
        }
    }

    // write private partials (fully overwritten -> no init kernel needed)
    #pragma unroll
    for (int j = 0; j < 4; ++j) {
        float2* mp = reinterpret_cast<float2*>(
            ws_meanp + (((size_t)rt * NLC + lc) * RT + 4 * rg + j) * DD);
        mp[dg] = macc[j];
    }
    if (lane < 8)
        ws_cntp[((size_t)rt * NLC + lc) * RT + wave * 8 + lane] = creg;
}

// ============================================================================
// K2: per-wave exact radix top-32 (keys in 64 VGPRs), softmax, padded static
// gather, mean-partial reduce, write out. Fully per-wave: zero __syncthreads.
// ============================================================================
__global__ __launch_bounds__(256, 3) void k_select(
    const float* __restrict__ vmat,
    const float* __restrict__ ws,
    float*       __restrict__ out)
{
    __shared__ unsigned int hist[4][256];         // 4 KB
    __shared__ unsigned int selKey[4][KEEP];
    __shared__ int          selIdx[4][KEEP];
    __shared__ float        wsel[4][KEEP];
    __shared__ int          selCnt[4], eqCnt[4];

    const int t    = threadIdx.x;
    const int wave = t >> 6;
    const int lane = t & 63;
    const int row  = blockIdx.x * 4 + wave;
    const int b    = row / LQ;

    const float* ws_sc    = ws;
    const float* ws_meanp = ws + WS_MEANP;
    const float* ws_cntp  = ws + WS_CNTP;

    // ---- load row scores, convert to order-preserving uint keys (64 VGPRs) --
    unsigned int key[64];
    {
        const float4* sg = reinterpret_cast<const float4*>(ws_sc) + (size_t)row * (LL / 4);
        #pragma unroll
        for (int i = 0; i < 16; ++i) {
            float4 f = sg[lane + 64 * i];
            float vals[4] = { f.x, f.y, f.z, f.w };
            #pragma unroll
            for (int c = 0; c < 4; ++c) {
                unsigned int u = __float_as_uint(vals[c]);
                key[4 * i + c] = ((int)u < 0) ? ~u : (u | 0x80000000u);
            }
        }
    }

    // ---- 4-pass radix select: exact 32nd-largest key + tie quota ------------
    unsigned int prefix = 0, quota = KEEP;
    #pragma unroll
    for (int pass = 0; pass < 4; ++pass) {
        const int shift = 24 - 8 * pass;
        const unsigned int hs = (pass == 0) ? 0u : (unsigned int)(32 - 8 * pass);
        reinterpret_cast<uint4*>(hist[wave])[lane] = make_uint4(0u, 0u, 0u, 0u);
        __asm__ volatile("s_waitcnt lgkmcnt(0)" ::: "memory");
        #pragma unroll
        for (int e = 0; e < 64; ++e) {
            bool act = (pass == 0) || ((key[e] >> hs) == prefix);
            if (act) atomicAdd(&hist[wave][(key[e] >> shift) & 255u], 1u);
        }
        __asm__ volatile("s_waitcnt lgkmcnt(0)" ::: "memory");
        uint4 h = reinterpret_cast<const uint4*>(hist[wave])[lane];
        unsigned int s4  = h.x + h.y + h.z + h.w;
        unsigned int suf = s4;                    // suffix-inclusive over lanes
        #pragma unroll
        for (int off = 1; off < 64; off <<= 1) {
            unsigned int v = (unsigned int)__shfl_down((int)suf, off);
            if (lane + off < 64) suf += v;
        }
        unsigned int above = suf - s4;            // count in lanes > this one
        bool cond = (suf >= quota) && (above < quota);
        unsigned int Bq = 0, nq = 0;
        if (cond) {
            unsigned int hb[4] = { h.x, h.y, h.z, h.w };
            unsigned int run = above;
            int Bj = 0;
            #pragma unroll
            for (int j = 3; j >= 0; --j) {
                unsigned int nb = run + hb[j];
                if (nb >= quota) { Bj = j; break; }
                run = nb;
            }
            Bq = (unsigned int)(lane * 4 + Bj);
            nq = quota - run;                     // still needed inside bucket
        }
        unsigned long long bal = __ballot(cond);
        int src = __ffsll(bal) - 1;               // exactly one lane
        Bq = (unsigned int)__shfl((int)Bq, src);
        nq = (unsigned int)__shfl((int)nq, src);
        prefix = (prefix << 8) | Bq;
        quota  = nq;
    }
    const unsigned int T = prefix;                // exact 32nd-largest key
    const bool take_eq = (T != MASKED_KEY);       // masked ties have 0 weight

    // ---- compact selected (val,idx) into LDS --------------------------------
    if (lane < KEEP) { wsel[wave][lane] = 0.f; selIdx[wave][lane] = 0; }
    if (lane == 0)   { selCnt[wave] = 0; eqCnt[wave] = 0; }
    __asm__ volatile("s_waitcnt lgkmcnt(0)" ::: "memory");
    #pragma unroll
    for (int e = 0; e < 64; ++e) {
        unsigned int k = key[e];
        if (k > T) {
            int slot = atomicAdd(&selCnt[wave], 1);
            selKey[wave][slot] = k;
            selIdx[wave][slot] = 256 * (e >> 2) + 4 * lane + (e & 3);
        } else if (take_eq && k == T) {
            int t2 = atomicAdd(&eqCnt[wave], 1);
            if (t2 < (int)quota) {
                int slot = atomicAdd(&selCnt[wave], 1);
                selKey[wave][slot] = k;
                selIdx[wave][slot] = 256 * (e >> 2) + 4 * lane + (e & 3);
            }
        }
    }
    __asm__ volatile("s_waitcnt lgkmcnt(0)" ::: "memory");
    const int S = selCnt[wave];

    // ---- mean-partial reduction ---------------------------------------------
    const int rtb = row >> 5, r = row & (RT - 1);
    float o = 0.f, cnt = 0.f;
    #pragma unroll
    for (int lc = 0; lc < NLC; ++lc) {
        o   += ws_meanp[(((size_t)rtb * NLC + lc) * RT + r) * DD + lane];
        cnt += ws_cntp[((size_t)rtb * NLC + lc) * RT + r];
    }
    if (cnt < 1.f) cnt = 1.f;
    o /= cnt;

    // ---- softmax over selected + padded static gather -----------------------
    if (S > 0) {
        float vj = -FLT_MAX;
        if (lane < S) {
            unsigned int kk = selKey[wave][lane];
            unsigned int u = (kk & 0x80000000u) ? (kk ^ 0x80000000u) : ~kk;
            vj = __uint_as_float(u);
        }
        float mx = vj;
        #pragma unroll
        for (int off = 1; off < 64; off <<= 1) mx = fmaxf(mx, __shfl_xor(mx, off));
        float e = (lane < S) ? expf(vj - mx) : 0.f;
        float sum = e;
        #pragma unroll
        for (int off = 1; off < 64; off <<= 1) sum += __shfl_xor(sum, off);
        if (lane < S) wsel[wave][lane] = e / sum;
        __asm__ volatile("s_waitcnt lgkmcnt(0)" ::: "memory");
        const float* vb = vmat + (size_t)b * LL * DD + lane;
        #pragma unroll
        for (int j = 0; j < KEEP; ++j) {          // independent loads, wj=0 pads
            float wj = wsel[wave][j];
            int   ij = selIdx[wave][j];
            o += wj * vb[(size_t)ij * DD];
        }
    }
    out[(size_t)row * DD + lane] = o;
}

// ============================================================================
// Fallback (proven round-1 monolith) in case ws_size < WS_TOTAL*4.
// ============================================================================
#define QT   2
#define NT   256
#define NTILES (LL / NT)

__global__ __launch_bounds__(NT, 4) void ga_fused_fb(
    const float* __restrict__ q, const float* __restrict__ kmat,
    const float* __restrict__ vmat, const int* __restrict__ mask,
    float* __restrict__ out)
{
    __shared__ float sc[QT][LL];
    __shared__ float q_s[QT][DD];
    __shared__ unsigned long long mbits[QT][LL / 64];
    __shared__ float redv[4][QT][DD];
    __shared__ float mean_s[QT][DD];
    __shared__ int   count_s[QT];
    __shared__ int   sel_idx[QT][KEEP];
    __shared__ float sel_val[QT][KEEP];
    __shared__ int   sel_cnt[QT];
    __shared__ float wred[4];
    __shared__ int   ired[4];
    __shared__ int   brk;
    __shared__ float wgt[QT][KEEP];

    const int t = threadIdx.x, wave = t >> 6, lane = t & 63;
    const int n0 = blockIdx.x * QT, b = n0 / LQ;

    if (t < QT) sel_cnt[t] = 0;
    if (t < QT * DD) q_s[t >> 6][t & 63] = q[(size_t)(n0 + (t >> 6)) * DD + (t & 63)];
    __syncthreads();

    const float4* q4_0 = reinterpret_cast<const float4*>(&q_s[0][0]);
    const float4* q4_1 = reinterpret_cast<const float4*>(&q_s[1][0]);
    for (int tile = 0; tile < NTILES; ++tile) {
        int l = tile * NT + t;
        const float4* kr = reinterpret_cast<const float4*>(kmat + (size_t)(b * LL + l) * DD);
        float d0 = 0.f, d1 = 0.f;
        #pragma unroll
        for (int i = 0; i < 16; ++i) {
            float4 kk = kr[i], qa = q4_0[i], qb = q4_1[i];
            d0 += kk.x * qa.x + kk.y * qa.y + kk.z * qa.z + kk.w * qa.w;
            d1 += kk.x * qb.x + kk.y * qb.y + kk.z * qb.z + kk.w * qb.w;
        }
        int mv0 = mask[(size_t)n0 * LL + l];
        int mv1 = mask[(size_t)(n0 + 1) * LL + l];
        unsigned long long b0 = __ballot(mv0 != 0);
        unsigned long long b1 = __ballot(mv1 != 0);
        if (lane == 0) { mbits[0][tile * 4 + wave] = b0; mbits[1][tile * 4 + wave] = b1; }
        sc[0][l] = mv0 ? d0 * 0.125f : -FLT_MAX;
        sc[1][l] = mv1 ? d1 * 0.125f : -FLT_MAX;
    }
    __syncthreads();

    if (wave < QT) {
        int c = (int)__popcll(mbits[wave][lane]);
        for (int off = 32; off >= 1; off >>= 1) c += __shfl_down(c, off);
        if (lane == 0) count_s[wave] = c;
    }
    {
        float acc0 = 0.f, acc1 = 0.f;
        const int g = wave, d = lane;
        for (int wi = 0; wi < LL / 64; ++wi) {
            unsigned long long w0 = mbits[0][wi], w1 = mbits[1][wi];
            const float* vp = vmat + (size_t)(b * LL + wi * 64 + g) * DD + d;
            #pragma unroll 4
            for (int ii = 0; ii < 16; ++ii) {
                int sh = g + 4 * ii;
                float vv = vp[(size_t)(4 * ii) * DD];
                if ((w0 >> sh) & 1ULL) acc0 += vv;
                if ((w1 >> sh) & 1ULL) acc1 += vv;
            }
        }
        redv[g][0][d] = acc0; redv[g][1][d] = acc1;
    }
    __syncthreads();
    if (t < QT * DD) {
        int qt = t >> 6, dd = t & 63;
        float s2 = redv[0][qt][dd] + redv[1][qt][dd] + redv[2][qt][dd] + redv[3][qt][dd];
        int c = count_s[qt]; if (c < 1) c = 1;
        mean_s[qt][dd] = s2 / (float)c;
    }
    __syncthreads();

    for (int qt = 0; qt < QT; ++qt) {
        for (int s = 0; s < KEEP; ++s) {
            float m = -FLT_MAX; int mi = LL;
            for (int j = 0; j < NTILES; ++j) {
                int l = j * NT + t;
                float val = sc[qt][l];
                if (val > m) { m = val; mi = l; }
            }
            for (int off = 32; off >= 1; off >>= 1) {
                float ov = __shfl_down(m, off);
                int   oi = __shfl_down(mi, off);
                if (ov > m || (ov == m && oi < mi)) { m = ov; mi = oi; }
            }
            if (lane == 0) { wred[wave] = m; ired[wave] = mi; }
            __syncthreads();
            if (t == 0) {
                float bv = wred[0]; int bi = ired[0];
                for (int w2 = 1; w2 < 4; ++w2) {
                    float ov = wred[w2]; int oi = ired[w2];
                    if (ov > bv || (ov == bv && oi < bi)) { bv = ov; bi = oi; }
                }
                if (bv > -FLT_MAX) {
                    sel_idx[qt][s] = bi; sel_val[qt][s] = bv; sel_cnt[qt] = s + 1;
                    sc[qt][bi] = -FLT_MAX; brk = 0;
                } else brk = 1;
            }
            __syncthreads();
            if (brk) break;
        }
    }

    if (wave < QT) {
        int qt = wave, S = sel_cnt[qt];
        if (S > 0) {
            float mx = sel_val[qt][0];
            float e = 0.f;
            if (lane < S) e = expf(sel_val[qt][lane] - mx);
            float ssum = e;
            for (int off = 32; off >= 1; off >>= 1) ssum += __shfl_xor(ssum, off);
            if (lane < S) wgt[qt][lane] = e / ssum;
        }
    }
    __syncthreads();
    if (wave < QT) {
        int qt = wave, S = sel_cnt[qt];
        float o = mean_s[qt][lane];
        for (int j = 0; j < S; ++j)
            o += wgt[qt][j] * vmat[(size_t)(b * LL + sel_idx[qt][j]) * DD + lane];
        out[(size_t)(n0 + qt) * DD + lane] = o;
    }
}

// ============================================================================
extern "C" void kernel_launch(void* const* d_in, const int* in_sizes, int n_in,
                              void* d_out, int out_size, void* d_ws, size_t ws_size,
                              hipStream_t stream) {
    const float* q    = (const float*)d_in[0];
    const float* kmat = (const float*)d_in[1];
    const float* vmat = (const float*)d_in[2];
    const int*   mask = (const int*)d_in[3];
    float* out = (float*)d_out;

    const size_t need = (size_t)WS_TOTAL * sizeof(float);   // ~71.4 MB
    if (ws_size >= need) {
        float* ws = (float*)d_ws;
        hipLaunchKernelGGL(k_scores_mean, dim3((NROWS / RT) * NLC), dim3(256),
                           0, stream, q, kmat, vmat, mask, ws);
        hipLaunchKernelGGL(k_select, dim3(NROWS / 4), dim3(256), 0, stream,
                           vmat, ws, out);
    } else {
        hipLaunchKernelGGL(ga_fused_fb, dim3(NROWS / QT), dim3(NT), 0, stream,
                           q, kmat, vmat, mask, out);
    }
}

// Round 6
// 398.373 us; speedup vs baseline: 5.2081x; 1.5138x over previous
//
#include <hip/hip_runtime.h>
#include <float.h>
#include <math.h>

// Problem constants (from reference setup_inputs)
#define LQ   512
#define LL   4096      // key length
#define DD   64        // d_qk == d_v
#define KEEP 32        // MAX_SET_SIZE
#define NB   8         // batches
#define NROWS (NB * LQ)    // 4096 flat query rows

// K1 tiling
#define RT    32           // query rows per block
#define NLC   4            // l-chunks (partials per row)
#define LC    (LL / NLC)   // 1024
#define LSP   128          // l's per staging round
#define NPAIR (LC / LSP)   // 8

// ---- ws layout (floats) ----------------------------------------------------
#define MEANP_SZ ((NROWS / RT) * NLC * RT * DD)
#define CNTP_SZ  ((NROWS / RT) * NLC * RT)
#define WS_MEANP (NROWS * LL)
#define WS_CNTP  (WS_MEANP + MEANP_SZ)
#define WS_TOTAL (WS_CNTP + CNTP_SZ)        // 71.4 MB (proven available in R4/R5)

#define MASKED_KEY 0x00800000u              // order-key of -FLT_MAX

__device__ __forceinline__ float dot4(float4 a, float4 b) {
    return a.x * b.x + a.y * b.y + a.z * b.z + a.w * b.w;
}

// ============================================================================
// K1: masked scores -> ws; per-block mean/count partials -> ws (no atomics).
// Block = [32 q-rows] x [1024 l-chunk], staged 128 l at a time.
// amdgpu_waves_per_eu(2,3): grid is 512 blocks = 2 blocks/CU, so capping the
// allocator's occupancy target at 3 waves/EU (>=170 VGPR budget) is free and
// prevents the 64-VGPR/8-wave squeeze that spilled ~350 MB in round 5.
// ============================================================================
__global__ __launch_bounds__(256)
__attribute__((amdgpu_waves_per_eu(2, 3)))
void k_scores_mean(
    const float* __restrict__ q,
    const float* __restrict__ kmat,
    const float* __restrict__ vmat,
    const int*   __restrict__ mask,
    float*       __restrict__ ws)
{
    __shared__ float4 Ss4[16 * LSP];              // 32 KB: K^T [dc][l], reused for V
    __shared__ unsigned long long mb[RT][2];      // ballot words per row (this pair)

    float* ws_sc    = ws;
    float* ws_meanp = ws + WS_MEANP;
    float* ws_cntp  = ws + WS_CNTP;

    const int t    = threadIdx.x;
    const int wave = t >> 6;
    const int lane = t & 63;
    const int rt   = blockIdx.x >> 2;             // 0..127
    const int lc   = blockIdx.x & (NLC - 1);      // 0..3
    const int n0   = rt * RT;
    const int b    = n0 / LQ;
    const int lbase = lc * LC;

    // wave-uniform q-row byte bases -> SGPRs (q loads become s_load_dwordx4)
    int qbase[8];
    #pragma unroll
    for (int p = 0; p < 8; ++p)
        qbase[p] = __builtin_amdgcn_readfirstlane((n0 + wave * 8 + p) * DD);

    // mean mapping: thread (rg = t>>5, dg = t&31) owns rows 4rg..4rg+3, dims 2dg..2dg+1
    const int dg = t & 31;
    const int rg = t >> 5;
    float2 macc[4];
    #pragma unroll
    for (int j = 0; j < 4; ++j) macc[j] = make_float2(0.f, 0.f);
    float creg = 0.f;                             // lane p<8: count for row wave*8+p

    const float4* kg = reinterpret_cast<const float4*>(kmat) + (size_t)b * LL * 16;
    const float4* vg = reinterpret_cast<const float4*>(vmat) + (size_t)b * LL * 16;
    float2* Vs2 = reinterpret_cast<float2*>(Ss4);

    for (int s = 0; s < NPAIR; ++s) {
        const int l0 = lbase + s * LSP;
        __syncthreads();                          // Ss free (prev mean done)

        // stage K transposed: wave w covers dc = w*4..w*4+3 (proven 0-conflict)
        #pragma unroll
        for (int i = 0; i < 2; ++i)
            #pragma unroll
            for (int j = 0; j < 4; ++j)
                Ss4[(wave * 4 + j) * LSP + lane + 64 * i] =
                    kg[(size_t)(l0 + lane + 64 * i) * 16 + wave * 4 + j];
        __syncthreads();

        // ---- scores: lane = l (two halves), wave rows wave*8..+7 ------------
        float acc0[8], acc1[8];
        #pragma unroll
        for (int p = 0; p < 8; ++p) { acc0[p] = 0.f; acc1[p] = 0.f; }
        #pragma unroll
        for (int dc = 0; dc < 16; ++dc) {
            float4 ka = Ss4[dc * LSP + lane];
            float4 kb = Ss4[dc * LSP + 64 + lane];
            #pragma unroll
            for (int p = 0; p < 8; ++p) {
                float4 q4 = *reinterpret_cast<const float4*>(q + qbase[p] + dc * 4);
                acc0[p] += dot4(ka, q4);
                acc1[p] += dot4(kb, q4);
            }
        }
        // mask load inline per row (short live range -> no register-pressure tax)
        #pragma unroll
        for (int p = 0; p < 8; ++p) {
            const int r = wave * 8 + p;
            int m0 = mask[(size_t)(n0 + r) * LL + l0 + lane];
            int m1 = mask[(size_t)(n0 + r) * LL + l0 + 64 + lane];
            unsigned long long b0 = __ballot(m0 != 0);
            unsigned long long b1 = __ballot(m1 != 0);
            if (lane == 0) { mb[r][0] = b0; mb[r][1] = b1; }
            if (lane == p) creg += (float)(__popcll(b0) + __popcll(b1));
            ws_sc[(size_t)(n0 + r) * LL + l0 + lane]      = m0 ? acc0[p] * 0.125f : -FLT_MAX;
            ws_sc[(size_t)(n0 + r) * LL + l0 + 64 + lane] = m1 ? acc1[p] * 0.125f : -FLT_MAX;
        }
        __syncthreads();                          // K reads done; mb visible

        // stage V natural (flat coalesced copy, 32 KB)
        #pragma unroll
        for (int i = 0; i < 8; ++i)
            Ss4[t + 256 * i] = vg[(size_t)l0 * 16 + t + 256 * i];
        __syncthreads();

        // ---- mean: thread (rg,dg), rows 4rg..+3, dims 2dg..+1, b64 reads ----
        #pragma unroll
        for (int lw = 0; lw < 2; ++lw) {
            unsigned long long w0 = mb[4 * rg + 0][lw];
            unsigned long long w1 = mb[4 * rg + 1][lw];
            unsigned long long w2 = mb[4 * rg + 2][lw];
            unsigned long long w3 = mb[4 * rg + 3][lw];
            #pragma unroll 8
            for (int l6 = 0; l6 < 64; ++l6) {
                float2 v2 = Vs2[(lw * 64 + l6) * 32 + dg];
                float m0 = (float)((w0 >> l6) & 1ULL);
                float m1 = (float)((w1 >> l6) & 1ULL);
                float m2 = (float)((w2 >> l6) & 1ULL);
                float m3 = (float)((w3 >> l6) & 1ULL);
                macc[0].x = fmaf(m0, v2.x, macc[0].x); macc[0].y = fmaf(m0, v2.y, macc[0].y);
                macc[1].x = fmaf(m1, v2.x, macc[1].x); macc[1].y = fmaf(m1, v2.y, macc[1].y);
                macc[2].x = fmaf(m2, v2.x, macc[2].x); macc[2].y = fmaf(m2, v2.y, macc[2].y);
                macc[3].x = fmaf(m3, v2.x, macc[3].x); macc[3].y = fmaf(m3, v2.y, macc[3].y);
            }
        }
    }

    // write private partials (fully overwritten -> no init kernel needed)
    #pragma unroll
    for (int j = 0; j < 4; ++j) {
        float2* mp = reinterpret_cast<float2*>(
            ws_meanp + (((size_t)rt * NLC + lc) * RT + 4 * rg + j) * DD);
        mp[dg] = macc[j];
    }
    if (lane < 8)
        ws_cntp[((size_t)rt * NLC + lc) * RT + wave * 8 + lane] = creg;
}

// ============================================================================
// K2: per-wave exact radix top-32 (keys in 64 VGPRs), softmax, padded static
// gather, mean-partial reduce, write out. Fully per-wave: zero __syncthreads.
// (unchanged from round 5 — 366 -> ~136 us, absmax 1.95e-3)
// ============================================================================
__global__ __launch_bounds__(256, 3) void k_select(
    const float* __restrict__ vmat,
    const float* __restrict__ ws,
    float*       __restrict__ out)
{
    __shared__ unsigned int hist[4][256];         // 4 KB
    __shared__ unsigned int selKey[4][KEEP];
    __shared__ int          selIdx[4][KEEP];
    __shared__ float        wsel[4][KEEP];
    __shared__ int          selCnt[4], eqCnt[4];

    const int t    = threadIdx.x;
    const int wave = t >> 6;
    const int lane = t & 63;
    const int row  = blockIdx.x * 4 + wave;
    const int b    = row / LQ;

    const float* ws_sc    = ws;
    const float* ws_meanp = ws + WS_MEANP;
    const float* ws_cntp  = ws + WS_CNTP;

    // ---- load row scores, convert to order-preserving uint keys (64 VGPRs) --
    unsigned int key[64];
    {
        const float4* sg = reinterpret_cast<const float4*>(ws_sc) + (size_t)row * (LL / 4);
        #pragma unroll
        for (int i = 0; i < 16; ++i) {
            float4 f = sg[lane + 64 * i];
            float vals[4] = { f.x, f.y, f.z, f.w };
            #pragma unroll
            for (int c = 0; c < 4; ++c) {
                unsigned int u = __float_as_uint(vals[c]);
                key[4 * i + c] = ((int)u < 0) ? ~u : (u | 0x80000000u);
            }
        }
    }

    // ---- 4-pass radix select: exact 32nd-largest key + tie quota ------------
    unsigned int prefix = 0, quota = KEEP;
    #pragma unroll
    for (int pass = 0; pass < 4; ++pass) {
        const int shift = 24 - 8 * pass;
        const unsigned int hs = (pass == 0) ? 0u : (unsigned int)(32 - 8 * pass);
        reinterpret_cast<uint4*>(hist[wave])[lane] = make_uint4(0u, 0u, 0u, 0u);
        __asm__ volatile("s_waitcnt lgkmcnt(0)" ::: "memory");
        #pragma unroll
        for (int e = 0; e < 64; ++e) {
            bool act = (pass == 0) || ((key[e] >> hs) == prefix);
            if (act) atomicAdd(&hist[wave][(key[e] >> shift) & 255u], 1u);
        }
        __asm__ volatile("s_waitcnt lgkmcnt(0)" ::: "memory");
        uint4 h = reinterpret_cast<const uint4*>(hist[wave])[lane];
        unsigned int s4  = h.x + h.y + h.z + h.w;
        unsigned int suf = s4;                    // suffix-inclusive over lanes
        #pragma unroll
        for (int off = 1; off < 64; off <<= 1) {
            unsigned int v = (unsigned int)__shfl_down((int)suf, off);
            if (lane + off < 64) suf += v;
        }
        unsigned int above = suf - s4;            // count in lanes > this one
        bool cond = (suf >= quota) && (above < quota);
        unsigned int Bq = 0, nq = 0;
        if (cond) {
            unsigned int hb[4] = { h.x, h.y, h.z, h.w };
            unsigned int run = above;
            int Bj = 0;
            #pragma unroll
            for (int j = 3; j >= 0; --j) {
                unsigned int nb = run + hb[j];
                if (nb >= quota) { Bj = j; break; }
                run = nb;
            }
            Bq = (unsigned int)(lane * 4 + Bj);
            nq = quota - run;                     // still needed inside bucket
        }
        unsigned long long bal = __ballot(cond);
        int src = __ffsll(bal) - 1;               // exactly one lane
        Bq = (unsigned int)__shfl((int)Bq, src);
        nq = (unsigned int)__shfl((int)nq, src);
        prefix = (prefix << 8) | Bq;
        quota  = nq;
    }
    const unsigned int T = prefix;                // exact 32nd-largest key
    const bool take_eq = (T != MASKED_KEY);       // masked ties have 0 weight

    // ---- compact selected (val,idx) into LDS --------------------------------
    if (lane < KEEP) { wsel[wave][lane] = 0.f; selIdx[wave][lane] = 0; }
    if (lane == 0)   { selCnt[wave] = 0; eqCnt[wave] = 0; }
    __asm__ volatile("s_waitcnt lgkmcnt(0)" ::: "memory");
    #pragma unroll
    for (int e = 0; e < 64; ++e) {
        unsigned int k = key[e];
        if (k > T) {
            int slot = atomicAdd(&selCnt[wave], 1);
            selKey[wave][slot] = k;
            selIdx[wave][slot] = 256 * (e >> 2) + 4 * lane + (e & 3);
        } else if (take_eq && k == T) {
            int t2 = atomicAdd(&eqCnt[wave], 1);
            if (t2 < (int)quota) {
                int slot = atomicAdd(&selCnt[wave], 1);
                selKey[wave][slot] = k;
                selIdx[wave][slot] = 256 * (e >> 2) + 4 * lane + (e & 3);
            }
        }
    }
    __asm__ volatile("s_waitcnt lgkmcnt(0)" ::: "memory");
    const int S = selCnt[wave];

    // ---- mean-partial reduction ---------------------------------------------
    const int rtb = row >> 5, r = row & (RT - 1);
    float o = 0.f, cnt = 0.f;
    #pragma unroll
    for (int lc = 0; lc < NLC; ++lc) {
        o   += ws_meanp[(((size_t)rtb * NLC + lc) * RT + r) * DD + lane];
        cnt += ws_cntp[((size_t)rtb * NLC + lc) * RT + r];
    }
    if (cnt < 1.f) cnt = 1.f;
    o /= cnt;

    // ---- softmax over selected + padded static gather -----------------------
    if (S > 0) {
        float vj = -FLT_MAX;
        if (lane < S) {
            unsigned int kk = selKey[wave][lane];
            unsigned int u = (kk & 0x80000000u) ? (kk ^ 0x80000000u) : ~kk;
            vj = __uint_as_float(u);
        }
        float mx = vj;
        #pragma unroll
        for (int off = 1; off < 64; off <<= 1) mx = fmaxf(mx, __shfl_xor(mx, off));
        float e = (lane < S) ? expf(vj - mx) : 0.f;
        float sum = e;
        #pragma unroll
        for (int off = 1; off < 64; off <<= 1) sum += __shfl_xor(sum, off);
        if (lane < S) wsel[wave][lane] = e / sum;
        __asm__ volatile("s_waitcnt lgkmcnt(0)" ::: "memory");
        const float* vb = vmat + (size_t)b * LL * DD + lane;
        #pragma unroll
        for (int j = 0; j < KEEP; ++j) {          // independent loads, wj=0 pads
            float wj = wsel[wave][j];
            int   ij = selIdx[wave][j];
            o += wj * vb[(size_t)ij * DD];
        }
    }
    out[(size_t)row * DD + lane] = o;
}

// ============================================================================
// Fallback (proven round-1 monolith) in case ws_size < WS_TOTAL*4.
// ============================================================================
#define QT   2
#define NT   256
#define NTILES (LL / NT)

__global__ __launch_bounds__(NT, 4) void ga_fused_fb(
    const float* __restrict__ q, const float* __restrict__ kmat,
    const float* __restrict__ vmat, const int* __restrict__ mask,
    float* __restrict__ out)
{
    __shared__ float sc[QT][LL];
    __shared__ float q_s[QT][DD];
    __shared__ unsigned long long mbits[QT][LL / 64];
    __shared__ float redv[4][QT][DD];
    __shared__ float mean_s[QT][DD];
    __shared__ int   count_s[QT];
    __shared__ int   sel_idx[QT][KEEP];
    __shared__ float sel_val[QT][KEEP];
    __shared__ int   sel_cnt[QT];
    __shared__ float wred[4];
    __shared__ int   ired[4];
    __shared__ int   brk;
    __shared__ float wgt[QT][KEEP];

    const int t = threadIdx.x, wave = t >> 6, lane = t & 63;
    const int n0 = blockIdx.x * QT, b = n0 / LQ;

    if (t < QT) sel_cnt[t] = 0;
    if (t < QT * DD) q_s[t >> 6][t & 63] = q[(size_t)(n0 + (t >> 6)) * DD + (t & 63)];
    __syncthreads();

    const float4* q4_0 = reinterpret_cast<const float4*>(&q_s[0][0]);
    const float4* q4_1 = reinterpret_cast<const float4*>(&q_s[1][0]);
    for (int tile = 0; tile < NTILES; ++tile) {
        int l = tile * NT + t;
        const float4* kr = reinterpret_cast<const float4*>(kmat + (size_t)(b * LL + l) * DD);
        float d0 = 0.f, d1 = 0.f;
        #pragma unroll
        for (int i = 0; i < 16; ++i) {
            float4 kk = kr[i], qa = q4_0[i], qb = q4_1[i];
            d0 += kk.x * qa.x + kk.y * qa.y + kk.z * qa.z + kk.w * qa.w;
            d1 += kk.x * qb.x + kk.y * qb.y + kk.z * qb.z + kk.w * qb.w;
        }
        int mv0 = mask[(size_t)n0 * LL + l];
        int mv1 = mask[(size_t)(n0 + 1) * LL + l];
        unsigned long long b0 = __ballot(mv0 != 0);
        unsigned long long b1 = __ballot(mv1 != 0);
        if (lane == 0) { mbits[0][tile * 4 + wave] = b0; mbits[1][tile * 4 + wave] = b1; }
        sc[0][l] = mv0 ? d0 * 0.125f : -FLT_MAX;
        sc[1][l] = mv1 ? d1 * 0.125f : -FLT_MAX;
    }
    __syncthreads();

    if (wave < QT) {
        int c = (int)__popcll(mbits[wave][lane]);
        for (int off = 32; off >= 1; off >>= 1) c += __shfl_down(c, off);
        if (lane == 0) count_s[wave] = c;
    }
    {
        float acc0 = 0.f, acc1 = 0.f;
        const int g = wave, d = lane;
        for (int wi = 0; wi < LL / 64; ++wi) {
            unsigned long long w0 = mbits[0][wi], w1 = mbits[1][wi];
            const float* vp = vmat + (size_t)(b * LL + wi * 64 + g) * DD + d;
            #pragma unroll 4
            for (int ii = 0; ii < 16; ++ii) {
                int sh = g + 4 * ii;
                float vv = vp[(size_t)(4 * ii) * DD];
                if ((w0 >> sh) & 1ULL) acc0 += vv;
                if ((w1 >> sh) & 1ULL) acc1 += vv;
            }
        }
        redv[g][0][d] = acc0; redv[g][1][d] = acc1;
    }
    __syncthreads();
    if (t < QT * DD) {
        int qt = t >> 6, dd = t & 63;
        float s2 = redv[0][qt][dd] + redv[1][qt][dd] + redv[2][qt][dd] + redv[3][qt][dd];
        int c = count_s[qt]; if (c < 1) c = 1;
        mean_s[qt][dd] = s2 / (float)c;
    }
    __syncthreads();

    for (int qt = 0; qt < QT; ++qt) {
        for (int s = 0; s < KEEP; ++s) {
            float m = -FLT_MAX; int mi = LL;
            for (int j = 0; j < NTILES; ++j) {
                int l = j * NT + t;
                float val = sc[qt][l];
                if (val > m) { m = val; mi = l; }
            }
            for (int off = 32; off >= 1; off >>= 1) {
                float ov = __shfl_down(m, off);
                int   oi = __shfl_down(mi, off);
                if (ov > m || (ov == m && oi < mi)) { m = ov; mi = oi; }
            }
            if (lane == 0) { wred[wave] = m; ired[wave] = mi; }
            __syncthreads();
            if (t == 0) {
                float bv = wred[0]; int bi = ired[0];
                for (int w2 = 1; w2 < 4; ++w2) {
                    float ov = wred[w2]; int oi = ired[w2];
                    if (ov > bv || (ov == bv && oi < bi)) { bv = ov; bi = oi; }
                }
                if (bv > -FLT_MAX) {
                    sel_idx[qt][s] = bi; sel_val[qt][s] = bv; sel_cnt[qt] = s + 1;
                    sc[qt][bi] = -FLT_MAX; brk = 0;
                } else brk = 1;
            }
            __syncthreads();
            if (brk) break;
        }
    }

    if (wave < QT) {
        int qt = wave, S = sel_cnt[qt];
        if (S > 0) {
            float mx = sel_val[qt][0];
            float e = 0.f;
            if (lane < S) e = expf(sel_val[qt][lane] - mx);
            float ssum = e;
            for (int off = 32; off >= 1; off >>= 1) ssum += __shfl_xor(ssum, off);
            if (lane < S) wgt[qt][lane] = e / ssum;
        }
    }
    __syncthreads();
    if (wave < QT) {
        int qt = wave, S = sel_cnt[qt];
        float o = mean_s[qt][lane];
        for (int j = 0; j < S; ++j)
            o += wgt[qt][j] * vmat[(size_t)(b * LL + sel_idx[qt][j]) * DD + lane];
        out[(size_t)(n0 + qt) * DD + lane] = o;
    }
}

// ============================================================================
extern "C" void kernel_launch(void* const* d_in, const int* in_sizes, int n_in,
                              void* d_out, int out_size, void* d_ws, size_t ws_size,
                              hipStream_t stream) {
    const float* q    = (const float*)d_in[0];
    const float* kmat = (const float*)d_in[1];
    const float* vmat = (const float*)d_in[2];
    const int*   mask = (const int*)d_in[3];
    float* out = (float*)d_out;

    const size_t need = (size_t)WS_TOTAL * sizeof(float);   // ~71.4 MB
    if (ws_size >= need) {
        float* ws = (float*)d_ws;
        hipLaunchKernelGGL(k_scores_mean, dim3((NROWS / RT) * NLC), dim3(256),
                           0, stream, q, kmat, vmat, mask, ws);
        hipLaunchKernelGGL(k_select, dim3(NROWS / 4), dim3(256), 0, stream,
                           vmat, ws, out);
    } else {
        hipLaunchKernelGGL(ga_fused_fb, dim3(NROWS / QT), dim3(NT), 0, stream,
                           q, kmat, vmat, mask, out);
    }
}

// Round 7
// 290.132 us; speedup vs baseline: 7.1511x; 1.3731x over previous
//
#include <hip/hip_runtime.h>
#include <float.h>
#include <math.h>

// Problem constants (from reference setup_inputs)
#define LQ   512
#define LL   4096      // key length
#define DD   64        // d_qk == d_v
#define KEEP 32        // MAX_SET_SIZE
#define NB   8         // batches
#define NROWS (NB * LQ)    // 4096 flat query rows

// K1 tiling
#define RT    32           // query rows per block
#define NLC   8            // l-chunks per row
#define LC    (LL / NLC)   // 512
#define LSP   128          // l's per staging round
#define NPAIR (LC / LSP)   // 4

// ---- ws layout --------------------------------------------------------------
// scores : [NROWS][LL] fp32                67.11 MB
// VT     : [NB][DD][LL] bf16                4.19 MB
#define WS_VT    (NROWS * LL)               // float offset of VT region
#define WS_TOTAL (WS_VT + (NB * DD * LL) / 2)   // 17,825,792 floats = 71.30 MB

#define MASKED_KEY 0x00800000u              // order-key of -FLT_MAX

typedef short  bf16x8 __attribute__((ext_vector_type(8)));
typedef float  f32x4  __attribute__((ext_vector_type(4)));

__device__ __forceinline__ float dot4(float4 a, float4 b) {
    return a.x * b.x + a.y * b.y + a.z * b.z + a.w * b.w;
}
__device__ __forceinline__ unsigned short f2bf(float f) {
    unsigned int u = __float_as_uint(f);
    return (unsigned short)((u + 0x7FFFu + ((u >> 16) & 1u)) >> 16);   // RNE
}

// ============================================================================
// P0: v[b][l][d] fp32 -> VT[b][d][l] bf16 (LDS tile transpose). 3 MB traffic.
// ============================================================================
#define TP_LB 256
__global__ __launch_bounds__(256) void k_vt(
    const float* __restrict__ v, unsigned short* __restrict__ vt)
{
    __shared__ unsigned short tile[DD][TP_LB + 8];   // +8 ushorts: bank de-phase
    const int t  = threadIdx.x;
    const int b  = blockIdx.x >> 4;                  // 16 blocks per batch
    const int l0 = (blockIdx.x & 15) * TP_LB;

    const float4* vg = reinterpret_cast<const float4*>(v + ((size_t)b * LL + l0) * DD);
    #pragma unroll
    for (int i = 0; i < 16; ++i) {
        int j = t + 256 * i;                         // f4 index: l = j>>4, dq = (j&15)*4
        float4 f = vg[j];
        int l = j >> 4, dq = (j & 15) * 4;
        tile[dq + 0][l] = f2bf(f.x);
        tile[dq + 1][l] = f2bf(f.y);
        tile[dq + 2][l] = f2bf(f.z);
        tile[dq + 3][l] = f2bf(f.w);
    }
    __syncthreads();
    const int d = t >> 2, seg = t & 3;               // 64 ushorts per thread
    const uint4* src = reinterpret_cast<const uint4*>(&tile[d][seg * 64]);
    uint4* dst = reinterpret_cast<uint4*>(vt + ((size_t)b * DD + d) * LL + l0 + seg * 64);
    #pragma unroll
    for (int i = 0; i < 8; ++i) dst[i] = src[i];
}

// ============================================================================
// P1: masked mean via bf16 MFMA. Block = 16 rows x all 64 d; wave w owns
// l-range [w*1024, w*1024+1024), all 4 d-tiles. A = mask as exact 0/1 bf16
// (built in-register), B = VT fragment (direct 16-B load, m97 B^T pattern).
// Writes out[n][d] = sum_v / clip(count,1). K2 later ADDS its context.
// ============================================================================
__global__ __launch_bounds__(256) void k_mean(
    const int* __restrict__ mask,
    const unsigned short* __restrict__ vt,
    float* __restrict__ out)
{
    __shared__ float sums[4][4][16][16];             // [wave][dtile][row][col] 16 KB
    __shared__ float cnt_s[4][16];

    const int t     = threadIdx.x;
    const int wave  = t >> 6;
    const int lane  = t & 63;
    const int n0    = blockIdx.x * 16;
    const int b     = n0 / LQ;
    const int row_a = lane & 15;                     // MFMA m / B n index
    const int chunk = lane >> 4;                     // k-quad

    const int* mrow = mask + (size_t)(n0 + row_a) * LL + wave * 1024 + chunk * 8;
    const unsigned short* vbase = vt + (size_t)b * DD * LL + wave * 1024 + chunk * 8;

    f32x4 acc[4];
    #pragma unroll
    for (int dt = 0; dt < 4; ++dt) acc[dt] = (f32x4){0.f, 0.f, 0.f, 0.f};
    int cnt = 0;

    for (int l0 = 0; l0 < 1024; l0 += 32) {
        int4 ma = *reinterpret_cast<const int4*>(mrow + l0);
        int4 mb = *reinterpret_cast<const int4*>(mrow + l0 + 4);
        cnt += (ma.x != 0) + (ma.y != 0) + (ma.z != 0) + (ma.w != 0)
             + (mb.x != 0) + (mb.y != 0) + (mb.z != 0) + (mb.w != 0);
        unsigned int p[4];
        p[0] = (ma.x ? 0x3F80u : 0u) | (ma.y ? 0x3F800000u : 0u);
        p[1] = (ma.z ? 0x3F80u : 0u) | (ma.w ? 0x3F800000u : 0u);
        p[2] = (mb.x ? 0x3F80u : 0u) | (mb.y ? 0x3F800000u : 0u);
        p[3] = (mb.z ? 0x3F80u : 0u) | (mb.w ? 0x3F800000u : 0u);
        bf16x8 afrag = *reinterpret_cast<bf16x8*>(p);
        #pragma unroll
        for (int dt = 0; dt < 4; ++dt) {
            bf16x8 bfrag = *reinterpret_cast<const bf16x8*>(
                vbase + (size_t)(dt * 16 + row_a) * LL + l0);
            acc[dt] = __builtin_amdgcn_mfma_f32_16x16x32_bf16(afrag, bfrag, acc[dt], 0, 0, 0);
        }
    }
    cnt += __shfl_xor(cnt, 16);
    cnt += __shfl_xor(cnt, 32);                      // all lanes: count[row_a] (this l-range)
    if (lane < 16) cnt_s[wave][lane] = (float)cnt;
    #pragma unroll
    for (int dt = 0; dt < 4; ++dt)
        #pragma unroll
        for (int r = 0; r < 4; ++r)
            sums[wave][dt][chunk * 4 + r][row_a] = acc[dt][r];
    __syncthreads();

    // final: thread t -> d = t&63, rows rgrp*4..+3
    const int d = t & 63, rgrp = t >> 6;
    #pragma unroll
    for (int rr = 0; rr < 4; ++rr) {
        const int row = rgrp * 4 + rr;
        float s = sums[0][d >> 4][row][d & 15] + sums[1][d >> 4][row][d & 15]
                + sums[2][d >> 4][row][d & 15] + sums[3][d >> 4][row][d & 15];
        float c = cnt_s[0][row] + cnt_s[1][row] + cnt_s[2][row] + cnt_s[3][row];
        if (c < 1.f) c = 1.f;
        out[(size_t)(n0 + row) * DD + d] = s / c;
    }
}

// ============================================================================
// K1: masked scores -> ws (fp32 VALU — precision-critical for top-k).
// Score-only now: no V stage, no mean phase, no ballots. 2 barriers/subtile.
// NLC=8 -> 1024 blocks = 4 blocks/CU (50% occupancy). waves_per_eu(2,4)
// keeps the allocator at a >=128-VGPR budget (kernel needs ~100; no spills).
// ============================================================================
__global__ __launch_bounds__(256)
__attribute__((amdgpu_waves_per_eu(2, 4)))
void k_scores(
    const float* __restrict__ q,
    const float* __restrict__ kmat,
    const int*   __restrict__ mask,
    float*       __restrict__ ws_sc)
{
    __shared__ float4 Ss4[16 * LSP];                 // 32 KB: K^T [dc][l]

    const int t    = threadIdx.x;
    const int wave = t >> 6;
    const int lane = t & 63;
    const int rt   = blockIdx.x >> 3;                // 0..127
    const int lc   = blockIdx.x & (NLC - 1);         // 0..7 -> XCD = blockIdx%8
    const int n0   = rt * RT;
    const int b    = n0 / LQ;
    const int lbase = lc * LC;

    int qbase[8];
    #pragma unroll
    for (int p = 0; p < 8; ++p)
        qbase[p] = __builtin_amdgcn_readfirstlane((n0 + wave * 8 + p) * DD);

    const float4* kg = reinterpret_cast<const float4*>(kmat) + (size_t)b * LL * 16;

    for (int s = 0; s < NPAIR; ++s) {
        const int l0 = lbase + s * LSP;
        __syncthreads();                             // Ss free
        #pragma unroll
        for (int i = 0; i < 2; ++i)
            #pragma unroll
            for (int j = 0; j < 4; ++j)
                Ss4[(wave * 4 + j) * LSP + lane + 64 * i] =
                    kg[(size_t)(l0 + lane + 64 * i) * 16 + wave * 4 + j];
        __syncthreads();

        float acc0[8], acc1[8];
        #pragma unroll
        for (int p = 0; p < 8; ++p) { acc0[p] = 0.f; acc1[p] = 0.f; }
        #pragma unroll
        for (int dc = 0; dc < 16; ++dc) {
            float4 ka = Ss4[dc * LSP + lane];
            float4 kb = Ss4[dc * LSP + 64 + lane];
            #pragma unroll
            for (int p = 0; p < 8; ++p) {
                float4 q4 = *reinterpret_cast<const float4*>(q + qbase[p] + dc * 4);
                acc0[p] += dot4(ka, q4);
                acc1[p] += dot4(kb, q4);
            }
        }
        #pragma unroll
        for (int p = 0; p < 8; ++p) {
            const int r = wave * 8 + p;
            int m0 = mask[(size_t)(n0 + r) * LL + l0 + lane];
            int m1 = mask[(size_t)(n0 + r) * LL + l0 + 64 + lane];
            ws_sc[(size_t)(n0 + r) * LL + l0 + lane]      = m0 ? acc0[p] * 0.125f : -FLT_MAX;
            ws_sc[(size_t)(n0 + r) * LL + l0 + 64 + lane] = m1 ? acc1[p] * 0.125f : -FLT_MAX;
        }
    }
}

// ============================================================================
// K2: per-wave exact radix top-32 (keys in 64 VGPRs), softmax, padded static
// gather; accumulates onto the mean already in out (written by k_mean).
// ============================================================================
__global__ __launch_bounds__(256, 3) void k_select(
    const float* __restrict__ vmat,
    const float* __restrict__ ws,
    float*       __restrict__ out)
{
    __shared__ unsigned int hist[4][256];
    __shared__ unsigned int selKey[4][KEEP];
    __shared__ int          selIdx[4][KEEP];
    __shared__ float        wsel[4][KEEP];
    __shared__ int          selCnt[4], eqCnt[4];

    const int t    = threadIdx.x;
    const int wave = t >> 6;
    const int lane = t & 63;
    const int row  = blockIdx.x * 4 + wave;
    const int b    = row / LQ;

    float o = out[(size_t)row * DD + lane];          // mean from k_mean (early load)

    // ---- load row scores -> order-preserving uint keys (64 VGPRs) -----------
    unsigned int key[64];
    {
        const float4* sg = reinterpret_cast<const float4*>(ws) + (size_t)row * (LL / 4);
        #pragma unroll
        for (int i = 0; i < 16; ++i) {
            float4 f = sg[lane + 64 * i];
            float vals[4] = { f.x, f.y, f.z, f.w };
            #pragma unroll
            for (int c = 0; c < 4; ++c) {
                unsigned int u = __float_as_uint(vals[c]);
                key[4 * i + c] = ((int)u < 0) ? ~u : (u | 0x80000000u);
            }
        }
    }

    // ---- 4-pass radix select: exact 32nd-largest key + tie quota ------------
    unsigned int prefix = 0, quota = KEEP;
    #pragma unroll
    for (int pass = 0; pass < 4; ++pass) {
        const int shift = 24 - 8 * pass;
        const unsigned int hs = (pass == 0) ? 0u : (unsigned int)(32 - 8 * pass);
        reinterpret_cast<uint4*>(hist[wave])[lane] = make_uint4(0u, 0u, 0u, 0u);
        __asm__ volatile("s_waitcnt lgkmcnt(0)" ::: "memory");
        #pragma unroll
        for (int e = 0; e < 64; ++e) {
            bool act = (pass == 0) || ((key[e] >> hs) == prefix);
            if (act) atomicAdd(&hist[wave][(key[e] >> shift) & 255u], 1u);
        }
        __asm__ volatile("s_waitcnt lgkmcnt(0)" ::: "memory");
        uint4 h = reinterpret_cast<const uint4*>(hist[wave])[lane];
        unsigned int s4  = h.x + h.y + h.z + h.w;
        unsigned int suf = s4;
        #pragma unroll
        for (int off = 1; off < 64; off <<= 1) {
            unsigned int v = (unsigned int)__shfl_down((int)suf, off);
            if (lane + off < 64) suf += v;
        }
        unsigned int above = suf - s4;
        bool cond = (suf >= quota) && (above < quota);
        unsigned int Bq = 0, nq = 0;
        if (cond) {
            unsigned int hb[4] = { h.x, h.y, h.z, h.w };
            unsigned int run = above;
            int Bj = 0;
            #pragma unroll
            for (int j = 3; j >= 0; --j) {
                unsigned int nb = run + hb[j];
                if (nb >= quota) { Bj = j; break; }
                run = nb;
            }
            Bq = (unsigned int)(lane * 4 + Bj);
            nq = quota - run;
        }
        unsigned long long bal = __ballot(cond);
        int src = __ffsll(bal) - 1;
        Bq = (unsigned int)__shfl((int)Bq, src);
        nq = (unsigned int)__shfl((int)nq, src);
        prefix = (prefix << 8) | Bq;
        quota  = nq;
    }
    const unsigned int T = prefix;
    const bool take_eq = (T != MASKED_KEY);

    // ---- compact selected (val,idx) into LDS --------------------------------
    if (lane < KEEP) { wsel[wave][lane] = 0.f; selIdx[wave][lane] = 0; }
    if (lane == 0)   { selCnt[wave] = 0; eqCnt[wave] = 0; }
    __asm__ volatile("s_waitcnt lgkmcnt(0)" ::: "memory");
    #pragma unroll
    for (int e = 0; e < 64; ++e) {
        unsigned int k = key[e];
        if (k > T) {
            int slot = atomicAdd(&selCnt[wave], 1);
            selKey[wave][slot] = k;
            selIdx[wave][slot] = 256 * (e >> 2) + 4 * lane + (e & 3);
        } else if (take_eq && k == T) {
            int t2 = atomicAdd(&eqCnt[wave], 1);
            if (t2 < (int)quota) {
                int slot = atomicAdd(&selCnt[wave], 1);
                selKey[wave][slot] = k;
                selIdx[wave][slot] = 256 * (e >> 2) + 4 * lane + (e & 3);
            }
        }
    }
    __asm__ volatile("s_waitcnt lgkmcnt(0)" ::: "memory");
    const int S = selCnt[wave];

    // ---- softmax over selected + padded static gather -----------------------
    if (S > 0) {
        float vj = -FLT_MAX;
        if (lane < S) {
            unsigned int kk = selKey[wave][lane];
            unsigned int u = (kk & 0x80000000u) ? (kk ^ 0x80000000u) : ~kk;
            vj = __uint_as_float(u);
        }
        float mx = vj;
        #pragma unroll
        for (int off = 1; off < 64; off <<= 1) mx = fmaxf(mx, __shfl_xor(mx, off));
        float e = (lane < S) ? expf(vj - mx) : 0.f;
        float sum = e;
        #pragma unroll
        for (int off = 1; off < 64; off <<= 1) sum += __shfl_xor(sum, off);
        if (lane < S) wsel[wave][lane] = e / sum;
        __asm__ volatile("s_waitcnt lgkmcnt(0)" ::: "memory");
        const float* vb = vmat + (size_t)b * LL * DD + lane;
        #pragma unroll
        for (int j = 0; j < KEEP; ++j) {
            float wj = wsel[wave][j];
            int   ij = selIdx[wave][j];
            o += wj * vb[(size_t)ij * DD];
        }
    }
    out[(size_t)row * DD + lane] = o;
}

// ============================================================================
// Fallback (proven round-1 monolith) in case ws_size < WS_TOTAL*4.
// ============================================================================
#define QT   2
#define NT   256
#define NTILES (LL / NT)

__global__ __launch_bounds__(NT, 4) void ga_fused_fb(
    const float* __restrict__ q, const float* __restrict__ kmat,
    const float* __restrict__ vmat, const int* __restrict__ mask,
    float* __restrict__ out)
{
    __shared__ float sc[QT][LL];
    __shared__ float q_s[QT][DD];
    __shared__ unsigned long long mbits[QT][LL / 64];
    __shared__ float redv[4][QT][DD];
    __shared__ float mean_s[QT][DD];
    __shared__ int   count_s[QT];
    __shared__ int   sel_idx[QT][KEEP];
    __shared__ float sel_val[QT][KEEP];
    __shared__ int   sel_cnt[QT];
    __shared__ float wred[4];
    __shared__ int   ired[4];
    __shared__ int   brk;
    __shared__ float wgt[QT][KEEP];

    const int t = threadIdx.x, wave = t >> 6, lane = t & 63;
    const int n0 = blockIdx.x * QT, b = n0 / LQ;

    if (t < QT) sel_cnt[t] = 0;
    if (t < QT * DD) q_s[t >> 6][t & 63] = q[(size_t)(n0 + (t >> 6)) * DD + (t & 63)];
    __syncthreads();

    const float4* q4_0 = reinterpret_cast<const float4*>(&q_s[0][0]);
    const float4* q4_1 = reinterpret_cast<const float4*>(&q_s[1][0]);
    for (int tile = 0; tile < NTILES; ++tile) {
        int l = tile * NT + t;
        const float4* kr = reinterpret_cast<const float4*>(kmat + (size_t)(b * LL + l) * DD);
        float d0 = 0.f, d1 = 0.f;
        #pragma unroll
        for (int i = 0; i < 16; ++i) {
            float4 kk = kr[i], qa = q4_0[i], qb = q4_1[i];
            d0 += kk.x * qa.x + kk.y * qa.y + kk.z * qa.z + kk.w * qa.w;
            d1 += kk.x * qb.x + kk.y * qb.y + kk.z * qb.z + kk.w * qb.w;
        }
        int mv0 = mask[(size_t)n0 * LL + l];
        int mv1 = mask[(size_t)(n0 + 1) * LL + l];
        unsigned long long b0 = __ballot(mv0 != 0);
        unsigned long long b1 = __ballot(mv1 != 0);
        if (lane == 0) { mbits[0][tile * 4 + wave] = b0; mbits[1][tile * 4 + wave] = b1; }
        sc[0][l] = mv0 ? d0 * 0.125f : -FLT_MAX;
        sc[1][l] = mv1 ? d1 * 0.125f : -FLT_MAX;
    }
    __syncthreads();

    if (wave < QT) {
        int c = (int)__popcll(mbits[wave][lane]);
        for (int off = 32; off >= 1; off >>= 1) c += __shfl_down(c, off);
        if (lane == 0) count_s[wave] = c;
    }
    {
        float acc0 = 0.f, acc1 = 0.f;
        const int g = wave, d = lane;
        for (int wi = 0; wi < LL / 64; ++wi) {
            unsigned long long w0 = mbits[0][wi], w1 = mbits[1][wi];
            const float* vp = vmat + (size_t)(b * LL + wi * 64 + g) * DD + d;
            #pragma unroll 4
            for (int ii = 0; ii < 16; ++ii) {
                int sh = g + 4 * ii;
                float vv = vp[(size_t)(4 * ii) * DD];
                if ((w0 >> sh) & 1ULL) acc0 += vv;
                if ((w1 >> sh) & 1ULL) acc1 += vv;
            }
        }
        redv[g][0][d] = acc0; redv[g][1][d] = acc1;
    }
    __syncthreads();
    if (t < QT * DD) {
        int qt = t >> 6, dd = t & 63;
        float s2 = redv[0][qt][dd] + redv[1][qt][dd] + redv[2][qt][dd] + redv[3][qt][dd];
        int c = count_s[qt]; if (c < 1) c = 1;
        mean_s[qt][dd] = s2 / (float)c;
    }
    __syncthreads();

    for (int qt = 0; qt < QT; ++qt) {
        for (int s = 0; s < KEEP; ++s) {
            float m = -FLT_MAX; int mi = LL;
            for (int j = 0; j < NTILES; ++j) {
                int l = j * NT + t;
                float val = sc[qt][l];
                if (val > m) { m = val; mi = l; }
            }
            for (int off = 32; off >= 1; off >>= 1) {
                float ov = __shfl_down(m, off);
                int   oi = __shfl_down(mi, off);
                if (ov > m || (ov == m && oi < mi)) { m = ov; mi = oi; }
            }
            if (lane == 0) { wred[wave] = m; ired[wave] = mi; }
            __syncthreads();
            if (t == 0) {
                float bv = wred[0]; int bi = ired[0];
                for (int w2 = 1; w2 < 4; ++w2) {
                    float ov = wred[w2]; int oi = ired[w2];
                    if (ov > bv || (ov == bv && oi < bi)) { bv = ov; bi = oi; }
                }
                if (bv > -FLT_MAX) {
                    sel_idx[qt][s] = bi; sel_val[qt][s] = bv; sel_cnt[qt] = s + 1;
                    sc[qt][bi] = -FLT_MAX; brk = 0;
                } else brk = 1;
            }
            __syncthreads();
            if (brk) break;
        }
    }

    if (wave < QT) {
        int qt = wave, S = sel_cnt[qt];
        if (S > 0) {
            float mx = sel_val[qt][0];
            float e = 0.f;
            if (lane < S) e = expf(sel_val[qt][lane] - mx);
            float ssum = e;
            for (int off = 32; off >= 1; off >>= 1) ssum += __shfl_xor(ssum, off);
            if (lane < S) wgt[qt][lane] = e / ssum;
        }
    }
    __syncthreads();
    if (wave < QT) {
        int qt = wave, S = sel_cnt[qt];
        float o = mean_s[qt][lane];
        for (int j = 0; j < S; ++j)
            o += wgt[qt][j] * vmat[(size_t)(b * LL + sel_idx[qt][j]) * DD + lane];
        out[(size_t)(n0 + qt) * DD + lane] = o;
    }
}

// ============================================================================
extern "C" void kernel_launch(void* const* d_in, const int* in_sizes, int n_in,
                              void* d_out, int out_size, void* d_ws, size_t ws_size,
                              hipStream_t stream) {
    const float* q    = (const float*)d_in[0];
    const float* kmat = (const float*)d_in[1];
    const float* vmat = (const float*)d_in[2];
    const int*   mask = (const int*)d_in[3];
    float* out = (float*)d_out;

    const size_t need = (size_t)WS_TOTAL * sizeof(float);   // 71.30 MB (< proven 71.37)
    if (ws_size >= need) {
        float* ws = (float*)d_ws;
        unsigned short* vt = (unsigned short*)(ws + WS_VT);
        hipLaunchKernelGGL(k_scores, dim3((NROWS / RT) * NLC), dim3(256), 0, stream,
                           q, kmat, mask, ws);
        hipLaunchKernelGGL(k_vt, dim3(NB * 16), dim3(256), 0, stream, vmat, vt);
        hipLaunchKernelGGL(k_mean, dim3(NROWS / 16), dim3(256), 0, stream,
                           mask, vt, out);
        hipLaunchKernelGGL(k_select, dim3(NROWS / 4), dim3(256), 0, stream,
                           vmat, ws, out);
    } else {
        hipLaunchKernelGGL(ga_fused_fb, dim3(NROWS / QT), dim3(NT), 0, stream,
                           q, kmat, vmat, mask, out);
    }
}